// Round 8
// baseline (260.838 us; speedup 1.0000x reference)
//
#include <hip/hip_runtime.h>
#include <math.h>

#define BATCH 2
#define SEQ   2048
#define HID   1024
#define NHEAD 16
#define HDIM  64
#define MTOT  (BATCH * SEQ)   // 4096
#define QKVN  (3 * HID)       // 3072
#define HBUF  ((size_t)BATCH * NHEAD * SEQ * HDIM)   // elems per q/k/v/vT buf

typedef _Float16 f16x8 __attribute__((ext_vector_type(8)));
typedef _Float16 f16x4 __attribute__((ext_vector_type(4)));
typedef float    f32x4 __attribute__((ext_vector_type(4)));

#define MFMA16(a, b, c) __builtin_amdgcn_mfma_f32_16x16x32_f16((a), (b), (c), 0, 0, 0)

#define GLDS16(gp, lp) __builtin_amdgcn_global_load_lds( \
    (const __attribute__((address_space(1))) void*)(gp), \
    (__attribute__((address_space(3))) void*)(lp), 16, 0, 0)

#if __has_builtin(__builtin_amdgcn_exp2f)
#define EXP2F(x) __builtin_amdgcn_exp2f(x)
#else
#define EXP2F(x) exp2f(x)
#endif

#define SCALE2 0.18033688011f     // 0.125 * log2(e)
#define MASK2  -14426.950408f     // -10000 * log2(e)  -> exp2 == 0 exactly
#define BIAS2  -4.0f              // headroom shift; cancels in normalization

// ---------------------------------------------------------------------------
// Fused prep:
//   blocks [0,2048):    hs fp32 -> fp16 PLAIN row-major [m][1024]
//   blocks [2048,6144): Wqkv fp32 [K][N] -> fp16 PLAIN [N][K];
//                       Wd -> fp16 [N][K] with the OLD 4-chunk swizzle
// ---------------------------------------------------------------------------
__global__ __launch_bounds__(256) void prep_kernel(
    const float* __restrict__ hs, const float* __restrict__ Wqkv,
    const float* __restrict__ Wd, _Float16* __restrict__ A_h,
    _Float16* __restrict__ outQ, _Float16* __restrict__ outD)
{
    __shared__ _Float16 T[32][36];
    const int gid = blockIdx.x;
    const int tid = threadIdx.x;
    if (gid < 2048) {
        const int ci = gid * 256 + tid;
        const int m = ci >> 7, cc = ci & 127;
        const float* src = hs + (size_t)m * 1024 + cc * 8;
        f16x8 o;
#pragma unroll
        for (int j = 0; j < 8; ++j) o[j] = (_Float16)src[j];
        *(f16x8*)(A_h + (size_t)m * 1024 + cc * 8) = o;
        return;
    }
    const int tb = gid - 2048;
    const int bx = tb & 127, k0 = (tb >> 7) * 32;
    const float* in;
    _Float16* out;
    int N, n0;
    bool isQ;
    if (bx < 96) { in = Wqkv; out = outQ; N = QKVN; n0 = bx * 32; isQ = true; }
    else         { in = Wd;   out = outD; N = HID;  n0 = (bx - 96) * 32; isQ = false; }
    {
        const int r = tid >> 3, c4 = (tid & 7) * 4;
        float4 v = *(const float4*)(in + (size_t)(k0 + r) * N + n0 + c4);
        T[r][c4 + 0] = (_Float16)v.x;
        T[r][c4 + 1] = (_Float16)v.y;
        T[r][c4 + 2] = (_Float16)v.z;
        T[r][c4 + 3] = (_Float16)v.w;
    }
    __syncthreads();
    {
        const int nn = tid >> 3, k4 = (tid & 7) * 4;
        const int n = n0 + nn;
        f16x4 o;
        o[0] = T[k4 + 0][nn]; o[1] = T[k4 + 1][nn];
        o[2] = T[k4 + 2][nn]; o[3] = T[k4 + 3][nn];
        if (isQ) {
            *(f16x4*)(out + (size_t)n * 1024 + k0 + k4) = o;   // plain [N][K]
        } else {
            const int pos = ((k4 >> 3) ^ (n & 3)), half = (k4 >> 2) & 1;
            *(f16x4*)(out + (size_t)n * 1024 + k0 + pos * 8 + half * 4) = o;
        }
    }
}

// ---------------------------------------------------------------------------
// QKV GEMM, 256x192 tile, grid 16x16 = 256 blocks = 1/CU. (round-6 verified)
// Epilogue: q and k PLAIN [b,h,s,d]; vT PLAIN transposed [b,h,d,s]
// (attn now fragment-loads K/V directly from global — no LDS swizzles).
// ---------------------------------------------------------------------------
__global__ __launch_bounds__(512, 1) void qkv_gemm8(
    const _Float16* __restrict__ A, const _Float16* __restrict__ Bt,
    const float* __restrict__ bias, _Float16* __restrict__ base)
{
    __shared__ _Float16 SA[2][16384];   // 256 rows x 64
    __shared__ _Float16 SB[2][12288];   // 192 rows x 64
    const int tid = threadIdx.x;
    const int w = tid >> 6, l = tid & 63;
    const int a = l & 15, q4 = l >> 4, a7 = a & 7;
    const int xc = blockIdx.x & 7, loc = blockIdx.x >> 3;
    const int bx = (xc & 3) * 4 + (loc & 3);
    const int by = (xc >> 2) * 8 + (loc >> 2);
    const int m0 = by * 256, n0 = bx * 192;
    const int wm = (w >> 2) * 128, wn = (w & 3) * 48;

    const int csw = (((tid & 7) ^ ((tid >> 3) & 7)) << 3);
    const _Float16* gA0 = A  + (size_t)(m0 + (tid >> 3)) * 1024 + csw;
    const _Float16* gB0 = Bt + (size_t)(n0 + (tid >> 3)) * 1024 + csw;

    auto stage = [&](int kt, int sl) {
        const size_t ko = (size_t)kt * 64;
#pragma unroll
        for (int u = 0; u < 4; ++u)
            GLDS16(gA0 + (size_t)(u * 64) * 1024 + ko, &SA[sl][0] + u * 4096 + tid * 8);
#pragma unroll
        for (int u = 0; u < 3; ++u)
            GLDS16(gB0 + (size_t)(u * 64) * 1024 + ko, &SB[sl][0] + u * 4096 + tid * 8);
    };

    stage(0, 0); stage(1, 1);
    asm volatile("s_waitcnt vmcnt(7)" ::: "memory");
    __builtin_amdgcn_sched_barrier(0);
    __builtin_amdgcn_s_barrier();
    __builtin_amdgcn_sched_barrier(0);

    f32x4 acc[8][3];
#pragma unroll
    for (int i = 0; i < 8; ++i)
#pragma unroll
        for (int j = 0; j < 3; ++j) acc[i][j] = (f32x4){0.f, 0.f, 0.f, 0.f};

#define FRG(SP, row_, ks_) \
    (*(const f16x8*)&(SP)[(row_) * 64 + ((((ks_) * 4 + q4) ^ a7) << 3)])

    f16x8 aL[4][2], aH[4][2], bf[3][2];
    {
#pragma unroll
        for (int i = 0; i < 4; ++i) {
            aL[i][0] = FRG(SA[0], wm + i * 16 + a, 0);
            aL[i][1] = FRG(SA[0], wm + i * 16 + a, 1);
        }
#pragma unroll
        for (int j = 0; j < 2; ++j) {
            bf[j][0] = FRG(SB[0], wn + j * 16 + a, 0);
            bf[j][1] = FRG(SB[0], wn + j * 16 + a, 1);
        }
    }

    for (int t = 0; t < 16; ++t) {
        const int sl = t & 1, nsl = sl ^ 1;
        const _Float16* sA = &SA[sl][0];
        const _Float16* sB = &SB[sl][0];

        if (t >= 1 && t <= 14) stage(t + 1, nsl);

        __builtin_amdgcn_s_setprio(1);
#pragma unroll
        for (int i = 0; i < 4; ++i)
#pragma unroll
            for (int j = 0; j < 2; ++j) {
                acc[i][j] = MFMA16(aL[i][0], bf[j][0], acc[i][j]);
                acc[i][j] = MFMA16(aL[i][1], bf[j][1], acc[i][j]);
            }
        __builtin_amdgcn_s_setprio(0);

        bf[2][0] = FRG(sB, wn + 32 + a, 0);
        bf[2][1] = FRG(sB, wn + 32 + a, 1);
        __builtin_amdgcn_s_setprio(1);
#pragma unroll
        for (int i = 0; i < 4; ++i) {
            acc[i][2] = MFMA16(aL[i][0], bf[2][0], acc[i][2]);
            acc[i][2] = MFMA16(aL[i][1], bf[2][1], acc[i][2]);
        }
        __builtin_amdgcn_s_setprio(0);

#pragma unroll
        for (int i = 0; i < 4; ++i) {
            aH[i][0] = FRG(sA, wm + 64 + i * 16 + a, 0);
            aH[i][1] = FRG(sA, wm + 64 + i * 16 + a, 1);
        }
        __builtin_amdgcn_s_setprio(1);
#pragma unroll
        for (int i = 0; i < 4; ++i)
#pragma unroll
            for (int j = 0; j < 3; ++j) {
                acc[i + 4][j] = MFMA16(aH[i][0], bf[j][0], acc[i + 4][j]);
                acc[i + 4][j] = MFMA16(aH[i][1], bf[j][1], acc[i + 4][j]);
            }
        __builtin_amdgcn_s_setprio(0);

        if (t < 15) {
            asm volatile("s_waitcnt vmcnt(0)" ::: "memory");
            __builtin_amdgcn_sched_barrier(0);
            __builtin_amdgcn_s_barrier();
            __builtin_amdgcn_sched_barrier(0);
            const _Float16* nA = &SA[nsl][0];
            const _Float16* nB = &SB[nsl][0];
#pragma unroll
            for (int i = 0; i < 4; ++i) {
                aL[i][0] = FRG(nA, wm + i * 16 + a, 0);
                aL[i][1] = FRG(nA, wm + i * 16 + a, 1);
            }
#pragma unroll
            for (int j = 0; j < 2; ++j) {
                bf[j][0] = FRG(nB, wn + j * 16 + a, 0);
                bf[j][1] = FRG(nB, wn + j * 16 + a, 1);
            }
        }
    }
#undef FRG

#pragma unroll
    for (int j = 0; j < 3; ++j) {
        const int n = n0 + wn + 16 * j + a;
        const float bv = bias[n];
        const int tq = n >> 10, h = (n >> 6) & 15, d = n & 63;
#pragma unroll
        for (int i = 0; i < 8; ++i) {
            const int mb = m0 + wm + 16 * i + q4 * 4;
            const int bb = mb >> 11, sb = mb & 2047;
            if (tq == 2) {
                // vT plain [b,h,d,s]; r walks s (contiguous) -> one f16x4
                f16x4 ov;
#pragma unroll
                for (int r = 0; r < 4; ++r) ov[r] = (_Float16)(acc[i][j][r] + bv);
                *(f16x4*)(base + 3 * HBUF
                          + ((size_t)((bb * 16 + h) * 64 + d)) * 2048 + sb) = ov;
            } else {
                // q and k both plain [b,h,s,d]
#pragma unroll
                for (int r = 0; r < 4; ++r) {
                    const _Float16 val = (_Float16)(acc[i][j][r] + bv);
                    base[(size_t)tq * HBUF
                         + ((size_t)(bb * 16 + h) * 2048 + sb + r) * 64 + d] = val;
                }
            }
        }
    }
}

// ---------------------------------------------------------------------------
// MFMA fp16 GEMM, TMx128xBK32 (dense projection): plain fp32 [M][N] store.
// ---------------------------------------------------------------------------
template<int EPI, int TM>
__global__ __launch_bounds__(256) void mfma_gemm(
    const _Float16* __restrict__ A, const _Float16* __restrict__ Bt,
    const float* __restrict__ bias, void* __restrict__ Cout,
    int M, int N, int K)
{
    __shared__ _Float16 As[TM * 32];
    __shared__ _Float16 Bs[128 * 32];
    constexpr int TI = TM / 32;
    constexpr int AR = TM / 4;

    const int tid = threadIdx.x;
    const int w = tid >> 6, l = tid & 63;
    const int a = l & 15, q4 = l >> 4;
    const int m0 = blockIdx.y * TM, n0 = blockIdx.x * 128;
    const int wm = (w >> 1) * (TM / 2), wn = (w & 1) * 64;

    f32x4 acc[TI][4];
#pragma unroll
    for (int i = 0; i < TI; ++i)
#pragma unroll
        for (int j = 0; j < 4; ++j) acc[i][j] = (f32x4){0.f, 0.f, 0.f, 0.f};

    const _Float16* gA = A + (size_t)(m0 + w * AR + (l >> 2)) * K + (l & 3) * 8;
    const _Float16* gB = Bt + (size_t)(n0 + w * 32 + (l >> 2)) * K + (l & 3) * 8;
    _Float16* sA = As + w * AR * 32;
    _Float16* sB = Bs + w * 1024;

    for (int k0 = 0; k0 < K; k0 += 32) {
#pragma unroll
        for (int u = 0; u < TM / 64; ++u)
            GLDS16(gA + (size_t)u * 16 * K + k0, sA + u * 512);
        GLDS16(gB + k0,          sB);
        GLDS16(gB + 16 * K + k0, sB + 512);
        __syncthreads();

        f16x8 af[TI], bf[4];
        const int pa = (q4 ^ (a & 3)) << 3;
#pragma unroll
        for (int i = 0; i < TI; ++i)
            af[i] = *(const f16x8*)&As[(wm + 16 * i + a) * 32 + pa];
#pragma unroll
        for (int j = 0; j < 4; ++j)
            bf[j] = *(const f16x8*)&Bs[(wn + 16 * j + a) * 32 + pa];
#pragma unroll
        for (int i = 0; i < TI; ++i)
#pragma unroll
            for (int j = 0; j < 4; ++j)
                acc[i][j] = MFMA16(af[i], bf[j], acc[i][j]);
        __syncthreads();
    }

    {
        float* C = (float*)Cout;
#pragma unroll
        for (int j = 0; j < 4; ++j) {
            const int n = n0 + wn + 16 * j + a;
            const float bv = bias[n];
#pragma unroll
            for (int i = 0; i < TI; ++i)
#pragma unroll
                for (int r = 0; r < 4; ++r) {
                    const int m = m0 + wm + 16 * i + q4 * 4 + r;
                    C[(size_t)m * N + n] = acc[i][j][r] + bv;
                }
        }
    }
}

// ---------------------------------------------------------------------------
// Paired-tile flash attention, no-max softmax — ZERO-LDS K/V version.
// K and V fragments load DIRECTLY from global (L1/L2-resident: 8 KB tiles,
// 16 blocks per (b,h) share an XCD via the bid&7 swizzle). LDS holds only
// the wave-private P buffer (8 KB/block) -> NO barriers anywhere: waves run
// independently, TLP hides all latency. V frags hoisted once per tile and
// shared by the hi/lo half-steps. (r7 lesson: attn was LDS-BW-bound, ~26
// KB/wave-tile x4-wave redundancy; this removes ~75% of LDS traffic.)
// ---------------------------------------------------------------------------
__global__ __launch_bounds__(256) void attn_mfma(
    const _Float16* __restrict__ qb, const _Float16* __restrict__ kb,
    const _Float16* __restrict__ vtb, _Float16* __restrict__ ctx)
{
    __shared__ _Float16 Ps[4][16 * 64];

    const int bid = blockIdx.x;
    const int jj = bid >> 3;
    const int bhIdx = (bid & 7) * 4 + (jj >> 4);   // 0..31
    const int p = jj & 15;
    const int b = bhIdx >> 4, h = bhIdx & 15;
    const int tid = threadIdx.x;
    const int w = tid >> 6, l = tid & 63;
    const int a = l & 15, q4 = l >> 4, a7 = a & 7;
    const size_t bh  = ((size_t)b * NHEAD + h) * SEQ;
    const size_t bhd = ((size_t)b * NHEAD + h) * 64;

    const int qHi = (31 - p) * 64 + w * 16;
    const int qLo = p * 64 + w * 16;
    const int ntiles = 32 - p;

    f16x8 qfh[2], qfl[2];
    {
        const _Float16* qp = qb + (bh + qHi + a) * 64;
        qfh[0] = *(const f16x8*)(qp + q4 * 8);
        qfh[1] = *(const f16x8*)(qp + 32 + q4 * 8);
        const _Float16* ql = qb + (bh + qLo + a) * 64;
        qfl[0] = *(const f16x8*)(ql + q4 * 8);
        qfl[1] = *(const f16x8*)(ql + 32 + q4 * 8);
    }

    f32x4 Oh[4], Ol[4];
#pragma unroll
    for (int c = 0; c < 4; ++c) {
        Oh[c] = (f32x4){0.f, 0.f, 0.f, 0.f};
        Ol[c] = (f32x4){0.f, 0.f, 0.f, 0.f};
    }
    float lh = 0.f, ll = 0.f;

    // direct-frag base pointers: K row (a), k-elems q4*8; V^T row (a), keys q4*8
    const _Float16* kfp = kb + (bh + a) * 64 + q4 * 8;
    const _Float16* vfp = vtb + (bhd + a) * 2048 + q4 * 8;
    _Float16* pbuf = &Ps[w][0];
    const int p0 = (q4 ^ a7) << 3;

    for (int t = 0; t < ntiles; ++t) {
        const int kt0 = t * 64;
        const bool doLo = (t <= p);

        // ---- K fragments direct from global (plain [b,h,s,d])
        f16x8 kf[4][2];
#pragma unroll
        for (int n0 = 0; n0 < 4; ++n0) {
            const _Float16* kr = kfp + (size_t)(kt0 + n0 * 16) * 64;
            kf[n0][0] = *(const f16x8*)(kr);
            kf[n0][1] = *(const f16x8*)(kr + 32);
        }
        // ---- V fragments direct from global (plain vT [b,h,d,s]); shared hi/lo
        f16x8 vf[4][2];
#pragma unroll
        for (int c = 0; c < 4; ++c) {
            const _Float16* vr = vfp + (size_t)(c * 16) * 2048 + kt0;
            vf[c][0] = *(const f16x8*)(vr);
            vf[c][1] = *(const f16x8*)(vr + 32);
        }

        f32x4 sh[4], sl[4];
        __builtin_amdgcn_s_setprio(1);
#pragma unroll
        for (int n0 = 0; n0 < 4; ++n0) {
            f32x4 c = (f32x4){0.f, 0.f, 0.f, 0.f};
            c = MFMA16(kf[n0][0], qfh[0], c);
            c = MFMA16(kf[n0][1], qfh[1], c);
            sh[n0] = c;
            if (doLo) {
                f32x4 d = (f32x4){0.f, 0.f, 0.f, 0.f};
                d = MFMA16(kf[n0][0], qfl[0], d);
                d = MFMA16(kf[n0][1], qfl[1], d);
                sl[n0] = d;
            }
        }
        __builtin_amdgcn_s_setprio(0);

        auto half_step = [&](f32x4 st[4], float& lrun, f32x4* O,
                             const bool maskT, const int qbase) {
            if (maskT) {
#pragma unroll
                for (int n0 = 0; n0 < 4; ++n0)
#pragma unroll
                    for (int r = 0; r < 4; ++r) {
                        const int kgl = kt0 + n0 * 16 + q4 * 4 + r;
                        st[n0][r] = (kgl > qbase + a) ? MASK2
                                                      : fmaf(st[n0][r], SCALE2, BIAS2);
                    }
            } else {
#pragma unroll
                for (int n0 = 0; n0 < 4; ++n0)
#pragma unroll
                    for (int r = 0; r < 4; ++r)
                        st[n0][r] = fmaf(st[n0][r], SCALE2, BIAS2);
            }
            float ls = 0.f;
#pragma unroll
            for (int n0 = 0; n0 < 4; ++n0)
#pragma unroll
                for (int r = 0; r < 4; ++r) {
                    const float pe = EXP2F(st[n0][r]);
                    st[n0][r] = pe;
                    ls += pe;
                }
            lrun += ls;
            // P write: keys 16n0+4q4..+3 consecutive -> one b64 per n0
            // (wave-private pbuf: no barrier needed, lgkm ordering only)
#pragma unroll
            for (int n0 = 0; n0 < 4; ++n0) {
                f16x4 pk;
#pragma unroll
                for (int r = 0; r < 4; ++r) pk[r] = (_Float16)st[n0][r];
                const int pos = (2 * n0 + (q4 >> 1)) ^ a7;
                *(f16x4*)&pbuf[a * 64 + pos * 8 + ((q4 & 1) << 2)] = pk;
            }
            f16x8 pf0 = *(const f16x8*)&pbuf[a * 64 + p0];
            f16x8 pf1 = *(const f16x8*)&pbuf[a * 64 + (p0 ^ 32)];
            __builtin_amdgcn_s_setprio(1);
#pragma unroll
            for (int c = 0; c < 4; ++c) {
                O[c] = MFMA16(vf[c][0], pf0, O[c]);
                O[c] = MFMA16(vf[c][1], pf1, O[c]);
            }
            __builtin_amdgcn_s_setprio(0);
        };

        half_step(sh, lh, Oh, t == 31 - p, qHi);
        if (doLo) half_step(sl, ll, Ol, t == p, qLo);
    }

    // ---- epilogue: reduce l, normalize, store ctx fp16 with GEMM-A swizzle
    auto finish = [&](float lrun, const f32x4* O, const int qbase) {
        float lt = lrun;
        lt += __shfl_xor(lt, 16);
        lt += __shfl_xor(lt, 32);
        const float inv = 1.0f / lt;
        const size_t row = (size_t)b * SEQ + qbase + a;
#pragma unroll
        for (int c = 0; c < 4; ++c) {
            const int d0 = c * 16 + q4 * 4;
            const int kcol = h * 64 + (d0 & ~31)
                           + ((((d0 >> 3) & 3) ^ (a & 3)) << 3) + (d0 & 7);
            f16x4 ov;
#pragma unroll
            for (int r = 0; r < 4; ++r) ov[r] = (_Float16)(O[c][r] * inv);
            *(f16x4*)(ctx + row * HID + kcol) = ov;
        }
    };
    finish(lh, Oh, qHi);
    finish(ll, Ol, qLo);
}

// ---------------------------------------------------------------------------
// WS: [A_h][WqkvT][WdT][q|k|v(unused)|vT][ctx]  (all fp16)
// ---------------------------------------------------------------------------
extern "C" void kernel_launch(void* const* d_in, const int* in_sizes, int n_in,
                              void* d_out, int out_size, void* d_ws, size_t ws_size,
                              hipStream_t stream) {
    const float* hs   = (const float*)d_in[0];
    const float* Wqkv = (const float*)d_in[2];
    const float* bqkv = (const float*)d_in[3];
    const float* Wd   = (const float*)d_in[4];
    const float* bd   = (const float*)d_in[5];

    _Float16* A_h   = (_Float16*)d_ws;
    _Float16* WqkvT = A_h + (size_t)MTOT * HID;
    _Float16* WdT   = WqkvT + (size_t)QKVN * HID;
    _Float16* qbuf  = WdT + (size_t)HID * HID;            // q | k | (v) | vT
    _Float16* ctxb  = qbuf + 4 * HBUF;

    prep_kernel<<<6144, 256, 0, stream>>>(hs, Wqkv, Wd, A_h, WqkvT, WdT);

    qkv_gemm8<<<256, 512, 0, stream>>>(A_h, WqkvT, bqkv, qbuf);

    attn_mfma<<<512, 256, 0, stream>>>(
        qbuf, qbuf + HBUF, qbuf + 3 * HBUF, ctxb);

    mfma_gemm<1, 64><<<dim3(HID / 128, MTOT / 64), 256, 0, stream>>>(
        ctxb, WdT, bd, d_out, MTOT, HID, HID);
}

// Round 9
// 179.953 us; speedup vs baseline: 1.4495x; 1.4495x over previous
//
#include <hip/hip_runtime.h>
#include <math.h>

#define BATCH 2
#define SEQ   2048
#define HID   1024
#define NHEAD 16
#define HDIM  64
#define MTOT  (BATCH * SEQ)   // 4096
#define QKVN  (3 * HID)       // 3072
#define HBUF  ((size_t)BATCH * NHEAD * SEQ * HDIM)   // elems per q/k/v/vT buf

typedef _Float16 f16x8 __attribute__((ext_vector_type(8)));
typedef _Float16 f16x4 __attribute__((ext_vector_type(4)));
typedef float    f32x4 __attribute__((ext_vector_type(4)));

#define MFMA16(a, b, c) __builtin_amdgcn_mfma_f32_16x16x32_f16((a), (b), (c), 0, 0, 0)

#define GLDS16(gp, lp) __builtin_amdgcn_global_load_lds( \
    (const __attribute__((address_space(1))) void*)(gp), \
    (__attribute__((address_space(3))) void*)(lp), 16, 0, 0)

#if __has_builtin(__builtin_amdgcn_exp2f)
#define EXP2F(x) __builtin_amdgcn_exp2f(x)
#else
#define EXP2F(x) exp2f(x)
#endif

#define SCALE2 0.18033688011f     // 0.125 * log2(e)
#define MASK2  -14426.950408f     // -10000 * log2(e)  -> exp2 == 0 exactly
#define BIAS2  -4.0f              // headroom shift; cancels in normalization

// ---------------------------------------------------------------------------
// Fused prep:
//   blocks [0,2048):    hs fp32 -> fp16 PLAIN row-major [m][1024]
//   blocks [2048,6144): Wqkv / Wd fp32 [K][N] -> fp16 PLAIN [N][K]
//   (all GEMM LDS swizzles live in the staging source addresses)
// ---------------------------------------------------------------------------
__global__ __launch_bounds__(256) void prep_kernel(
    const float* __restrict__ hs, const float* __restrict__ Wqkv,
    const float* __restrict__ Wd, _Float16* __restrict__ A_h,
    _Float16* __restrict__ outQ, _Float16* __restrict__ outD)
{
    __shared__ _Float16 T[32][36];
    const int gid = blockIdx.x;
    const int tid = threadIdx.x;
    if (gid < 2048) {
        const int ci = gid * 256 + tid;
        const int m = ci >> 7, cc = ci & 127;
        const float* src = hs + (size_t)m * 1024 + cc * 8;
        f16x8 o;
#pragma unroll
        for (int j = 0; j < 8; ++j) o[j] = (_Float16)src[j];
        *(f16x8*)(A_h + (size_t)m * 1024 + cc * 8) = o;
        return;
    }
    const int tb = gid - 2048;
    const int bx = tb & 127, k0 = (tb >> 7) * 32;
    const float* in;
    _Float16* out;
    int N, n0;
    if (bx < 96) { in = Wqkv; out = outQ; N = QKVN; n0 = bx * 32; }
    else         { in = Wd;   out = outD; N = HID;  n0 = (bx - 96) * 32; }
    {
        const int r = tid >> 3, c4 = (tid & 7) * 4;
        float4 v = *(const float4*)(in + (size_t)(k0 + r) * N + n0 + c4);
        T[r][c4 + 0] = (_Float16)v.x;
        T[r][c4 + 1] = (_Float16)v.y;
        T[r][c4 + 2] = (_Float16)v.z;
        T[r][c4 + 3] = (_Float16)v.w;
    }
    __syncthreads();
    {
        const int nn = tid >> 3, k4 = (tid & 7) * 4;
        const int n = n0 + nn;
        f16x4 o;
        o[0] = T[k4 + 0][nn]; o[1] = T[k4 + 1][nn];
        o[2] = T[k4 + 2][nn]; o[3] = T[k4 + 3][nn];
        *(f16x4*)(out + (size_t)n * 1024 + k0 + k4) = o;   // plain [N][K]
    }
}

// ---------------------------------------------------------------------------
// QKV GEMM, 256x192 tile, grid 16x16 = 256 blocks = 1/CU. (r6-verified)
// Epilogue: q plain / k row-swizzled / vT transposed+chunk-swizzled —
// exactly the formats the r6 attention staging consumes.
// ---------------------------------------------------------------------------
__global__ __launch_bounds__(512, 1) void qkv_gemm8(
    const _Float16* __restrict__ A, const _Float16* __restrict__ Bt,
    const float* __restrict__ bias, _Float16* __restrict__ base)
{
    __shared__ _Float16 SA[2][16384];   // 256 rows x 64
    __shared__ _Float16 SB[2][12288];   // 192 rows x 64
    const int tid = threadIdx.x;
    const int w = tid >> 6, l = tid & 63;
    const int a = l & 15, q4 = l >> 4, a7 = a & 7;
    const int xc = blockIdx.x & 7, loc = blockIdx.x >> 3;
    const int bx = (xc & 3) * 4 + (loc & 3);
    const int by = (xc >> 2) * 8 + (loc >> 2);
    const int m0 = by * 256, n0 = bx * 192;
    const int wm = (w >> 2) * 128, wn = (w & 3) * 48;

    const int csw = (((tid & 7) ^ ((tid >> 3) & 7)) << 3);
    const _Float16* gA0 = A  + (size_t)(m0 + (tid >> 3)) * 1024 + csw;
    const _Float16* gB0 = Bt + (size_t)(n0 + (tid >> 3)) * 1024 + csw;

    auto stage = [&](int kt, int sl) {
        const size_t ko = (size_t)kt * 64;
#pragma unroll
        for (int u = 0; u < 4; ++u)
            GLDS16(gA0 + (size_t)(u * 64) * 1024 + ko, &SA[sl][0] + u * 4096 + tid * 8);
#pragma unroll
        for (int u = 0; u < 3; ++u)
            GLDS16(gB0 + (size_t)(u * 64) * 1024 + ko, &SB[sl][0] + u * 4096 + tid * 8);
    };

    stage(0, 0); stage(1, 1);
    asm volatile("s_waitcnt vmcnt(7)" ::: "memory");
    __builtin_amdgcn_sched_barrier(0);
    __builtin_amdgcn_s_barrier();
    __builtin_amdgcn_sched_barrier(0);

    f32x4 acc[8][3];
#pragma unroll
    for (int i = 0; i < 8; ++i)
#pragma unroll
        for (int j = 0; j < 3; ++j) acc[i][j] = (f32x4){0.f, 0.f, 0.f, 0.f};

#define FRG(SP, row_, ks_) \
    (*(const f16x8*)&(SP)[(row_) * 64 + ((((ks_) * 4 + q4) ^ a7) << 3)])

    f16x8 aL[4][2], aH[4][2], bf[3][2];
    {
#pragma unroll
        for (int i = 0; i < 4; ++i) {
            aL[i][0] = FRG(SA[0], wm + i * 16 + a, 0);
            aL[i][1] = FRG(SA[0], wm + i * 16 + a, 1);
        }
#pragma unroll
        for (int j = 0; j < 2; ++j) {
            bf[j][0] = FRG(SB[0], wn + j * 16 + a, 0);
            bf[j][1] = FRG(SB[0], wn + j * 16 + a, 1);
        }
    }

    for (int t = 0; t < 16; ++t) {
        const int sl = t & 1, nsl = sl ^ 1;
        const _Float16* sA = &SA[sl][0];
        const _Float16* sB = &SB[sl][0];

        if (t >= 1 && t <= 14) stage(t + 1, nsl);

        __builtin_amdgcn_s_setprio(1);
#pragma unroll
        for (int i = 0; i < 4; ++i)
#pragma unroll
            for (int j = 0; j < 2; ++j) {
                acc[i][j] = MFMA16(aL[i][0], bf[j][0], acc[i][j]);
                acc[i][j] = MFMA16(aL[i][1], bf[j][1], acc[i][j]);
            }
        __builtin_amdgcn_s_setprio(0);

        bf[2][0] = FRG(sB, wn + 32 + a, 0);
        bf[2][1] = FRG(sB, wn + 32 + a, 1);
        __builtin_amdgcn_s_setprio(1);
#pragma unroll
        for (int i = 0; i < 4; ++i) {
            acc[i][2] = MFMA16(aL[i][0], bf[2][0], acc[i][2]);
            acc[i][2] = MFMA16(aL[i][1], bf[2][1], acc[i][2]);
        }
        __builtin_amdgcn_s_setprio(0);

#pragma unroll
        for (int i = 0; i < 4; ++i) {
            aH[i][0] = FRG(sA, wm + 64 + i * 16 + a, 0);
            aH[i][1] = FRG(sA, wm + 64 + i * 16 + a, 1);
        }
        __builtin_amdgcn_s_setprio(1);
#pragma unroll
        for (int i = 0; i < 4; ++i)
#pragma unroll
            for (int j = 0; j < 3; ++j) {
                acc[i + 4][j] = MFMA16(aH[i][0], bf[j][0], acc[i + 4][j]);
                acc[i + 4][j] = MFMA16(aH[i][1], bf[j][1], acc[i + 4][j]);
            }
        __builtin_amdgcn_s_setprio(0);

        if (t < 15) {
            asm volatile("s_waitcnt vmcnt(0)" ::: "memory");
            __builtin_amdgcn_sched_barrier(0);
            __builtin_amdgcn_s_barrier();
            __builtin_amdgcn_sched_barrier(0);
            const _Float16* nA = &SA[nsl][0];
            const _Float16* nB = &SB[nsl][0];
#pragma unroll
            for (int i = 0; i < 4; ++i) {
                aL[i][0] = FRG(nA, wm + i * 16 + a, 0);
                aL[i][1] = FRG(nA, wm + i * 16 + a, 1);
            }
#pragma unroll
            for (int j = 0; j < 2; ++j) {
                bf[j][0] = FRG(nB, wn + j * 16 + a, 0);
                bf[j][1] = FRG(nB, wn + j * 16 + a, 1);
            }
        }
    }
#undef FRG

    // ---- epilogue: q plain / k row-swizzled / vT transposed+swizzled (r6)
#pragma unroll
    for (int j = 0; j < 3; ++j) {
        const int n = n0 + wn + 16 * j + a;
        const float bv = bias[n];
        const int tq = n >> 10, h = (n >> 6) & 15, d = n & 63;
#pragma unroll
        for (int i = 0; i < 8; ++i) {
            const int mb = m0 + wm + 16 * i + q4 * 4;
            const int bb = mb >> 11, sb = mb & 2047;
            if (tq == 2) {
                f16x4 ov;
#pragma unroll
                for (int r = 0; r < 4; ++r) ov[r] = (_Float16)(acc[i][j][r] + bv);
                const size_t off =
                    ((size_t)((bb * 16 + h) * 64 + d)) * 2048
                    + (sb & ~63)
                    + ((((sb >> 3) & 7) ^ (d & 7)) << 3) + (sb & 7);
                *(f16x4*)(base + 3 * HBUF + off) = ov;
            } else if (tq == 1) {
#pragma unroll
                for (int r = 0; r < 4; ++r) {
                    const int s = sb + r;
                    const _Float16 val = (_Float16)(acc[i][j][r] + bv);
                    const int dk = ((((d >> 3) ^ (s & 7)) & 7) << 3) | (d & 7);
                    base[HBUF + ((size_t)(bb * 16 + h) * 2048 + s) * 64 + dk] = val;
                }
            } else {
#pragma unroll
                for (int r = 0; r < 4; ++r) {
                    const _Float16 val = (_Float16)(acc[i][j][r] + bv);
                    base[((size_t)(bb * 16 + h) * 2048 + sb + r) * 64 + d] = val;
                }
            }
        }
    }
}

// ---------------------------------------------------------------------------
// Dense projection GEMM on the qkv template: 128x128 tile, grid 32x8 = 256
// blocks = 1/CU, BK=64, 8 waves (2M x 4N), XOR-8 pre-swizzled-source staging,
// 1 vmcnt(0)+barrier per K-tile. A = ctx (plain fp16), B = WdT (plain [N][K]).
// Epilogue: plain fp32 [M][N] + bias.
// ---------------------------------------------------------------------------
__global__ __launch_bounds__(512, 1) void dense_gemm8(
    const _Float16* __restrict__ A, const _Float16* __restrict__ Bt,
    const float* __restrict__ bias, float* __restrict__ C)
{
    __shared__ _Float16 SA[2][8192];    // 128 rows x 64
    __shared__ _Float16 SB[2][8192];
    const int tid = threadIdx.x;
    const int w = tid >> 6, l = tid & 63;
    const int a = l & 15, q4 = l >> 4, a7 = a & 7;
    const int xc = blockIdx.x & 7, loc = blockIdx.x >> 3;
    const int bx = loc >> 2;            // 0..7
    const int by = xc * 4 + (loc & 3);  // 0..31
    const int m0 = by * 128, n0 = bx * 128;
    const int wm = (w >> 2) * 64, wn = (w & 3) * 32;

    const int csw = (((tid & 7) ^ ((tid >> 3) & 7)) << 3);
    const _Float16* gA0 = A  + (size_t)(m0 + (tid >> 3)) * 1024 + csw;
    const _Float16* gB0 = Bt + (size_t)(n0 + (tid >> 3)) * 1024 + csw;

    auto stage = [&](int kt, int sl) {
        const size_t ko = (size_t)kt * 64;
        GLDS16(gA0 + ko,                     &SA[sl][0] + tid * 8);
        GLDS16(gA0 + (size_t)64 * 1024 + ko, &SA[sl][0] + 4096 + tid * 8);
        GLDS16(gB0 + ko,                     &SB[sl][0] + tid * 8);
        GLDS16(gB0 + (size_t)64 * 1024 + ko, &SB[sl][0] + 4096 + tid * 8);
    };

    stage(0, 0); stage(1, 1);
    asm volatile("s_waitcnt vmcnt(4)" ::: "memory");
    __builtin_amdgcn_sched_barrier(0);
    __builtin_amdgcn_s_barrier();
    __builtin_amdgcn_sched_barrier(0);

    f32x4 acc[4][2];
#pragma unroll
    for (int i = 0; i < 4; ++i)
#pragma unroll
        for (int j = 0; j < 2; ++j) acc[i][j] = (f32x4){0.f, 0.f, 0.f, 0.f};

#define FRG(SP, row_, ks_) \
    (*(const f16x8*)&(SP)[(row_) * 64 + ((((ks_) * 4 + q4) ^ a7) << 3)])

    for (int t = 0; t < 16; ++t) {
        const int sl = t & 1, nsl = sl ^ 1;
        const _Float16* sA = &SA[sl][0];
        const _Float16* sB = &SB[sl][0];

        if (t >= 1 && t <= 14) stage(t + 1, nsl);

        f16x8 af[4][2], bfr[2][2];
#pragma unroll
        for (int j = 0; j < 2; ++j) {
            bfr[j][0] = FRG(sB, wn + j * 16 + a, 0);
            bfr[j][1] = FRG(sB, wn + j * 16 + a, 1);
        }
#pragma unroll
        for (int i = 0; i < 4; ++i) {
            af[i][0] = FRG(sA, wm + i * 16 + a, 0);
            af[i][1] = FRG(sA, wm + i * 16 + a, 1);
        }
        __builtin_amdgcn_s_setprio(1);
#pragma unroll
        for (int i = 0; i < 4; ++i)
#pragma unroll
            for (int j = 0; j < 2; ++j) {
                acc[i][j] = MFMA16(af[i][0], bfr[j][0], acc[i][j]);
                acc[i][j] = MFMA16(af[i][1], bfr[j][1], acc[i][j]);
            }
        __builtin_amdgcn_s_setprio(0);

        if (t < 15) {
            asm volatile("s_waitcnt vmcnt(0)" ::: "memory");
            __builtin_amdgcn_sched_barrier(0);
            __builtin_amdgcn_s_barrier();
            __builtin_amdgcn_sched_barrier(0);
        }
    }
#undef FRG

#pragma unroll
    for (int j = 0; j < 2; ++j) {
        const int n = n0 + wn + 16 * j + a;
        const float bv = bias[n];
#pragma unroll
        for (int i = 0; i < 4; ++i)
#pragma unroll
            for (int r = 0; r < 4; ++r) {
                const int m = m0 + wm + 16 * i + q4 * 4 + r;
                C[(size_t)m * 1024 + n] = acc[i][j][r] + bv;
            }
    }
}

// ---------------------------------------------------------------------------
// Paired-tile flash attention (r6-verified structure) + V-fragment hoist:
// V frags read from LDS ONCE per tile, shared by hi/lo half-steps (was
// re-read per half-step; cuts ~1/3 of V LDS-read traffic — attn is
// LDS-BW-bound per r7/r8 evidence). ctx store now PLAIN (dense GEMM
// swizzles via staging addresses instead).
// ---------------------------------------------------------------------------
__global__ __launch_bounds__(256, 2) void attn_mfma(
    const _Float16* __restrict__ qb, const _Float16* __restrict__ kb,
    const _Float16* __restrict__ vtb, _Float16* __restrict__ ctx)
{
    __shared__ _Float16 Ks[2][64 * 64];
    __shared__ _Float16 VT[2][64 * 64];
    __shared__ _Float16 Ps[4][16 * 64];

    const int bid = blockIdx.x;
    const int jj = bid >> 3;
    const int bhIdx = (bid & 7) * 4 + (jj >> 4);   // 0..31
    const int p = jj & 15;
    const int b = bhIdx >> 4, h = bhIdx & 15;
    const int tid = threadIdx.x;
    const int w = tid >> 6, l = tid & 63;
    const int a = l & 15, q4 = l >> 4, a7 = a & 7;
    const size_t bh  = ((size_t)b * NHEAD + h) * SEQ;
    const size_t bhd = ((size_t)b * NHEAD + h) * 64;

    const int qHi = (31 - p) * 64 + w * 16;
    const int qLo = p * 64 + w * 16;
    const int ntiles = 32 - p;

    f16x8 qfh[2], qfl[2];
    {
        const _Float16* qp = qb + (bh + qHi + a) * 64;
        qfh[0] = *(const f16x8*)(qp + q4 * 8);
        qfh[1] = *(const f16x8*)(qp + 32 + q4 * 8);
        const _Float16* ql = qb + (bh + qLo + a) * 64;
        qfl[0] = *(const f16x8*)(ql + q4 * 8);
        qfl[1] = *(const f16x8*)(ql + 32 + q4 * 8);
    }

    f32x4 Oh[4], Ol[4];
#pragma unroll
    for (int c = 0; c < 4; ++c) {
        Oh[c] = (f32x4){0.f, 0.f, 0.f, 0.f};
        Ol[c] = (f32x4){0.f, 0.f, 0.f, 0.f};
    }
    float lh = 0.f, ll = 0.f;

    const _Float16* kg = kb + (bh + w * 16) * 64 + l * 8;
    const int vrow = w * 16 + (l >> 3);
    const _Float16* vg = vtb + (bhd + vrow) * 2048 + (l & 7) * 8;
    _Float16* pbuf = &Ps[w][0];
    const int p0 = (q4 ^ a7) << 3;

    auto stage = [&](int t, int buf) {
        _Float16* ksl = &Ks[buf][0] + w * 1024 + l * 8;
        const _Float16* kt = kg + (size_t)t * 4096;
        GLDS16(kt,       ksl);
        GLDS16(kt + 512, ksl + 512);
        _Float16* vtl = &VT[buf][0] + vrow * 64 + (l & 7) * 8;
        GLDS16(vg + t * 64,            vtl);
        GLDS16(vg + t * 64 + 8 * 2048, vtl + 512);
    };

    stage(0, 0);

    for (int t = 0; t < ntiles; ++t) {
        __syncthreads();                 // tile t landed; prev-iter LDS reads drained
        if (t + 1 < ntiles) stage(t + 1, (t + 1) & 1);

        const _Float16* ksb  = &Ks[t & 1][0];
        const _Float16* vbuf = &VT[t & 1][0];
        const int kt0 = t * 64;
        const bool doLo = (t <= p);

        // ---- V fragments hoisted: one LDS read set per tile, shared hi/lo
        f16x8 vf[4][2];
#pragma unroll
        for (int c = 0; c < 4; ++c) {
            vf[c][0] = *(const f16x8*)&vbuf[(c * 16 + a) * 64 + p0];
            vf[c][1] = *(const f16x8*)&vbuf[(c * 16 + a) * 64 + (p0 ^ 32)];
        }

        f32x4 sh[4], sl[4];
        __builtin_amdgcn_s_setprio(1);
#pragma unroll
        for (int n0 = 0; n0 < 4; ++n0) {
            f16x8 kf0 = *(const f16x8*)&ksb[(n0 * 16 + a) * 64 + p0];
            f16x8 kf1 = *(const f16x8*)&ksb[(n0 * 16 + a) * 64 + (p0 ^ 32)];
            f32x4 c = (f32x4){0.f, 0.f, 0.f, 0.f};
            c = MFMA16(kf0, qfh[0], c);
            c = MFMA16(kf1, qfh[1], c);
            sh[n0] = c;
            if (doLo) {
                f32x4 d = (f32x4){0.f, 0.f, 0.f, 0.f};
                d = MFMA16(kf0, qfl[0], d);
                d = MFMA16(kf1, qfl[1], d);
                sl[n0] = d;
            }
        }
        __builtin_amdgcn_s_setprio(0);

        auto half_step = [&](f32x4 st[4], float& lrun, f32x4* O,
                             const bool maskT, const int qbase) {
            if (maskT) {
#pragma unroll
                for (int n0 = 0; n0 < 4; ++n0)
#pragma unroll
                    for (int r = 0; r < 4; ++r) {
                        const int kgl = kt0 + n0 * 16 + q4 * 4 + r;
                        st[n0][r] = (kgl > qbase + a) ? MASK2
                                                      : fmaf(st[n0][r], SCALE2, BIAS2);
                    }
            } else {
#pragma unroll
                for (int n0 = 0; n0 < 4; ++n0)
#pragma unroll
                    for (int r = 0; r < 4; ++r)
                        st[n0][r] = fmaf(st[n0][r], SCALE2, BIAS2);
            }
            float ls = 0.f;
#pragma unroll
            for (int n0 = 0; n0 < 4; ++n0)
#pragma unroll
                for (int r = 0; r < 4; ++r) {
                    const float pe = EXP2F(st[n0][r]);
                    st[n0][r] = pe;
                    ls += pe;
                }
            lrun += ls;
            // P write: keys 16n0+4q4..+3 consecutive -> one b64 per n0
#pragma unroll
            for (int n0 = 0; n0 < 4; ++n0) {
                f16x4 pk;
#pragma unroll
                for (int r = 0; r < 4; ++r) pk[r] = (_Float16)st[n0][r];
                const int pos = (2 * n0 + (q4 >> 1)) ^ a7;
                *(f16x4*)&pbuf[a * 64 + pos * 8 + ((q4 & 1) << 2)] = pk;
            }
            f16x8 pf0 = *(const f16x8*)&pbuf[a * 64 + p0];
            f16x8 pf1 = *(const f16x8*)&pbuf[a * 64 + (p0 ^ 32)];
            __builtin_amdgcn_s_setprio(1);
#pragma unroll
            for (int c = 0; c < 4; ++c) {
                O[c] = MFMA16(vf[c][0], pf0, O[c]);
                O[c] = MFMA16(vf[c][1], pf1, O[c]);
            }
            __builtin_amdgcn_s_setprio(0);
        };

        half_step(sh, lh, Oh, t == 31 - p, qHi);
        if (doLo) half_step(sl, ll, Ol, t == p, qLo);
    }

    // ---- epilogue: reduce l, normalize, store ctx fp16 PLAIN [b*S+q][h*64+d]
    auto finish = [&](float lrun, const f32x4* O, const int qbase) {
        float lt = lrun;
        lt += __shfl_xor(lt, 16);
        lt += __shfl_xor(lt, 32);
        const float inv = 1.0f / lt;
        const size_t row = (size_t)b * SEQ + qbase + a;
#pragma unroll
        for (int c = 0; c < 4; ++c) {
            const int kcol = h * 64 + c * 16 + q4 * 4;
            f16x4 ov;
#pragma unroll
            for (int r = 0; r < 4; ++r) ov[r] = (_Float16)(O[c][r] * inv);
            *(f16x4*)(ctx + row * HID + kcol) = ov;
        }
    };
    finish(lh, Oh, qHi);
    finish(ll, Ol, qLo);
}

// ---------------------------------------------------------------------------
// WS: [A_h][WqkvT][WdT][q|k(sw)|v(unused)|vT(sw)][ctx]  (all fp16)
// ---------------------------------------------------------------------------
extern "C" void kernel_launch(void* const* d_in, const int* in_sizes, int n_in,
                              void* d_out, int out_size, void* d_ws, size_t ws_size,
                              hipStream_t stream) {
    const float* hs   = (const float*)d_in[0];
    const float* Wqkv = (const float*)d_in[2];
    const float* bqkv = (const float*)d_in[3];
    const float* Wd   = (const float*)d_in[4];
    const float* bd   = (const float*)d_in[5];

    _Float16* A_h   = (_Float16*)d_ws;
    _Float16* WqkvT = A_h + (size_t)MTOT * HID;
    _Float16* WdT   = WqkvT + (size_t)QKVN * HID;
    _Float16* qbuf  = WdT + (size_t)HID * HID;            // q | k(sw) | (v) | vT(sw)
    _Float16* ctxb  = qbuf + 4 * HBUF;

    prep_kernel<<<6144, 256, 0, stream>>>(hs, Wqkv, Wd, A_h, WqkvT, WdT);

    qkv_gemm8<<<256, 512, 0, stream>>>(A_h, WqkvT, bqkv, qbuf);

    attn_mfma<<<512, 256, 0, stream>>>(
        qbuf, qbuf + HBUF, qbuf + 3 * HBUF, ctxb);

    dense_gemm8<<<256, 512, 0, stream>>>(ctxb, WdT, bd, (float*)d_out);
}

// Round 11
// 177.881 us; speedup vs baseline: 1.4664x; 1.0116x over previous
//
#include <hip/hip_runtime.h>
#include <math.h>

#define BATCH 2
#define SEQ   2048
#define HID   1024
#define NHEAD 16
#define HDIM  64
#define MTOT  (BATCH * SEQ)   // 4096
#define QKVN  (3 * HID)       // 3072
#define HBUF  ((size_t)BATCH * NHEAD * SEQ * HDIM)   // elems per q/k/v/vT buf

typedef _Float16 f16x8 __attribute__((ext_vector_type(8)));
typedef _Float16 f16x4 __attribute__((ext_vector_type(4)));
typedef float    f32x4 __attribute__((ext_vector_type(4)));

#define MFMA16(a, b, c) __builtin_amdgcn_mfma_f32_16x16x32_f16((a), (b), (c), 0, 0, 0)

#define GLDS16(gp, lp) __builtin_amdgcn_global_load_lds( \
    (const __attribute__((address_space(1))) void*)(gp), \
    (__attribute__((address_space(3))) void*)(lp), 16, 0, 0)

#if __has_builtin(__builtin_amdgcn_exp2f)
#define EXP2F(x) __builtin_amdgcn_exp2f(x)
#else
#define EXP2F(x) exp2f(x)
#endif

#define SCALE2 0.18033688011f     // 0.125 * log2(e)
#define MASKV  -14426.950408f     // -10000 * log2(e)  -> exp2 == 0 exactly
#define BIAS2  -4.0f              // headroom shift; cancels in normalization

// ---------------------------------------------------------------------------
// Fused prep:
//   blocks [0,2048):    hs fp32 -> fp16 PLAIN row-major [m][1024] (float4 x2)
//   blocks [2048,6144): Wqkv / Wd fp32 [K][N] -> fp16 PLAIN [N][K]
// ---------------------------------------------------------------------------
__global__ __launch_bounds__(256) void prep_kernel(
    const float* __restrict__ hs, const float* __restrict__ Wqkv,
    const float* __restrict__ Wd, _Float16* __restrict__ A_h,
    _Float16* __restrict__ outQ, _Float16* __restrict__ outD)
{
    __shared__ _Float16 T[32][36];
    const int gid = blockIdx.x;
    const int tid = threadIdx.x;
    if (gid < 2048) {
        const int ci = gid * 256 + tid;
        const int m = ci >> 7, cc = ci & 127;
        const float* src = hs + (size_t)m * 1024 + cc * 8;
        const float4 v0 = *(const float4*)(src);
        const float4 v1 = *(const float4*)(src + 4);
        f16x8 o;
        o[0] = (_Float16)v0.x; o[1] = (_Float16)v0.y;
        o[2] = (_Float16)v0.z; o[3] = (_Float16)v0.w;
        o[4] = (_Float16)v1.x; o[5] = (_Float16)v1.y;
        o[6] = (_Float16)v1.z; o[7] = (_Float16)v1.w;
        *(f16x8*)(A_h + (size_t)m * 1024 + cc * 8) = o;
        return;
    }
    const int tb = gid - 2048;
    const int bx = tb & 127, k0 = (tb >> 7) * 32;
    const float* in;
    _Float16* out;
    int N, n0;
    if (bx < 96) { in = Wqkv; out = outQ; N = QKVN; n0 = bx * 32; }
    else         { in = Wd;   out = outD; N = HID;  n0 = (bx - 96) * 32; }
    {
        const int r = tid >> 3, c4 = (tid & 7) * 4;
        float4 v = *(const float4*)(in + (size_t)(k0 + r) * N + n0 + c4);
        T[r][c4 + 0] = (_Float16)v.x;
        T[r][c4 + 1] = (_Float16)v.y;
        T[r][c4 + 2] = (_Float16)v.z;
        T[r][c4 + 3] = (_Float16)v.w;
    }
    __syncthreads();
    {
        const int nn = tid >> 3, k4 = (tid & 7) * 4;
        const int n = n0 + nn;
        f16x4 o;
        o[0] = T[k4 + 0][nn]; o[1] = T[k4 + 1][nn];
        o[2] = T[k4 + 2][nn]; o[3] = T[k4 + 3][nn];
        *(f16x4*)(out + (size_t)n * 1024 + k0 + k4) = o;   // plain [N][K]
    }
}

// ---------------------------------------------------------------------------
// QKV GEMM, 256x192 tile, grid 16x16 = 256 blocks = 1/CU. (r6-verified loop)
// NEW epilogue: q/k routed through LDS (staging buffer is dead post-K-loop)
// for a layout transpose -> fully-coalesced f16x8 global stores (old path
// was 2-byte scalar stores, ~2/3 of qkv write bytes). vT keeps the direct
// f16x4 scatter. Sout[256][192] chunk-XOR swizzled (aligned 16B reads,
// bounded write conflicts). Numerics & output formats unchanged.
// ---------------------------------------------------------------------------
__global__ __launch_bounds__(512, 1) void qkv_gemm8(
    const _Float16* __restrict__ A, const _Float16* __restrict__ Bt,
    const float* __restrict__ bias, _Float16* __restrict__ base)
{
    __shared__ _Float16 SMEM[57344];   // 112 KB: A0|A1|B0|B1, reused as Sout
#define SA_P(sl) (SMEM + (sl) * 16384)
#define SB_P(sl) (SMEM + 32768 + (sl) * 12288)

    const int tid = threadIdx.x;
    const int w = tid >> 6, l = tid & 63;
    const int a = l & 15, q4 = l >> 4, a7 = a & 7;
    const int xc = blockIdx.x & 7, loc = blockIdx.x >> 3;
    const int bx = (xc & 3) * 4 + (loc & 3);
    const int by = (xc >> 2) * 8 + (loc >> 2);
    const int m0 = by * 256, n0 = bx * 192;
    const int wm = (w >> 2) * 128, wn = (w & 3) * 48;

    const int csw = (((tid & 7) ^ ((tid >> 3) & 7)) << 3);
    const _Float16* gA0 = A  + (size_t)(m0 + (tid >> 3)) * 1024 + csw;
    const _Float16* gB0 = Bt + (size_t)(n0 + (tid >> 3)) * 1024 + csw;

    auto stage = [&](int kt, int sl) {
        const size_t ko = (size_t)kt * 64;
#pragma unroll
        for (int u = 0; u < 4; ++u)
            GLDS16(gA0 + (size_t)(u * 64) * 1024 + ko, SA_P(sl) + u * 4096 + tid * 8);
#pragma unroll
        for (int u = 0; u < 3; ++u)
            GLDS16(gB0 + (size_t)(u * 64) * 1024 + ko, SB_P(sl) + u * 4096 + tid * 8);
    };

    stage(0, 0); stage(1, 1);
    asm volatile("s_waitcnt vmcnt(7)" ::: "memory");
    __builtin_amdgcn_sched_barrier(0);
    __builtin_amdgcn_s_barrier();
    __builtin_amdgcn_sched_barrier(0);

    f32x4 acc[8][3];
#pragma unroll
    for (int i = 0; i < 8; ++i)
#pragma unroll
        for (int j = 0; j < 3; ++j) acc[i][j] = (f32x4){0.f, 0.f, 0.f, 0.f};

#define FRG(SP, row_, ks_) \
    (*(const f16x8*)&(SP)[(row_) * 64 + ((((ks_) * 4 + q4) ^ a7) << 3)])

    f16x8 aL[4][2], aH[4][2], bf[3][2];
    {
#pragma unroll
        for (int i = 0; i < 4; ++i) {
            aL[i][0] = FRG(SA_P(0), wm + i * 16 + a, 0);
            aL[i][1] = FRG(SA_P(0), wm + i * 16 + a, 1);
        }
#pragma unroll
        for (int j = 0; j < 2; ++j) {
            bf[j][0] = FRG(SB_P(0), wn + j * 16 + a, 0);
            bf[j][1] = FRG(SB_P(0), wn + j * 16 + a, 1);
        }
    }

    for (int t = 0; t < 16; ++t) {
        const int sl = t & 1, nsl = sl ^ 1;
        const _Float16* sA = SA_P(sl);
        const _Float16* sB = SB_P(sl);

        if (t >= 1 && t <= 14) stage(t + 1, nsl);

        __builtin_amdgcn_s_setprio(1);
#pragma unroll
        for (int i = 0; i < 4; ++i)
#pragma unroll
            for (int j = 0; j < 2; ++j) {
                acc[i][j] = MFMA16(aL[i][0], bf[j][0], acc[i][j]);
                acc[i][j] = MFMA16(aL[i][1], bf[j][1], acc[i][j]);
            }
        __builtin_amdgcn_s_setprio(0);

        bf[2][0] = FRG(sB, wn + 32 + a, 0);
        bf[2][1] = FRG(sB, wn + 32 + a, 1);
        __builtin_amdgcn_s_setprio(1);
#pragma unroll
        for (int i = 0; i < 4; ++i) {
            acc[i][2] = MFMA16(aL[i][0], bf[2][0], acc[i][2]);
            acc[i][2] = MFMA16(aL[i][1], bf[2][1], acc[i][2]);
        }
        __builtin_amdgcn_s_setprio(0);

#pragma unroll
        for (int i = 0; i < 4; ++i) {
            aH[i][0] = FRG(sA, wm + 64 + i * 16 + a, 0);
            aH[i][1] = FRG(sA, wm + 64 + i * 16 + a, 1);
        }
        __builtin_amdgcn_s_setprio(1);
#pragma unroll
        for (int i = 0; i < 4; ++i)
#pragma unroll
            for (int j = 0; j < 3; ++j) {
                acc[i + 4][j] = MFMA16(aH[i][0], bf[j][0], acc[i + 4][j]);
                acc[i + 4][j] = MFMA16(aH[i][1], bf[j][1], acc[i + 4][j]);
            }
        __builtin_amdgcn_s_setprio(0);

        if (t < 15) {
            asm volatile("s_waitcnt vmcnt(0)" ::: "memory");
            __builtin_amdgcn_sched_barrier(0);
            __builtin_amdgcn_s_barrier();
            __builtin_amdgcn_sched_barrier(0);
            const _Float16* nA = SA_P(nsl);
            const _Float16* nB = SB_P(nsl);
#pragma unroll
            for (int i = 0; i < 4; ++i) {
                aL[i][0] = FRG(nA, wm + i * 16 + a, 0);
                aL[i][1] = FRG(nA, wm + i * 16 + a, 1);
            }
#pragma unroll
            for (int j = 0; j < 2; ++j) {
                bf[j][0] = FRG(nB, wn + j * 16 + a, 0);
                bf[j][1] = FRG(nB, wn + j * 16 + a, 1);
            }
        }
    }
#undef FRG

    // ---- epilogue stage 1: acc -> Sout (q/k) with chunk-XOR swizzle;
    //      vT chunk keeps the direct f16x4 scatter (was already vectorized).
    __syncthreads();                     // all frag reads done; SMEM reusable
    _Float16* const Sout = SMEM;         // [256][192], col chunk ^= row&7
#pragma unroll
    for (int j = 0; j < 3; ++j) {
        const int n = n0 + wn + 16 * j + a;
        const float bv = bias[n];
        const int tq = n >> 10, h = (n >> 6) & 15, d = n & 63;
        const int nloc = wn + 16 * j + a;
#pragma unroll
        for (int i = 0; i < 8; ++i) {
            const int mloc = wm + 16 * i + q4 * 4;
            if (tq == 2) {
                const int mb = m0 + mloc;
                const int bb = mb >> 11, sb = mb & 2047;
                f16x4 ov;
#pragma unroll
                for (int r = 0; r < 4; ++r) ov[r] = (_Float16)(acc[i][j][r] + bv);
                const size_t off =
                    ((size_t)((bb * 16 + h) * 64 + d)) * 2048
                    + (sb & ~63)
                    + ((((sb >> 3) & 7) ^ (d & 7)) << 3) + (sb & 7);
                *(f16x4*)(base + 3 * HBUF + off) = ov;
            } else {
#pragma unroll
                for (int r = 0; r < 4; ++r) {
                    const int m2 = mloc + r;
                    const int col = (nloc & 0xC0)
                                  + (((((nloc >> 3) & 7)) ^ (m2 & 7)) << 3)
                                  + (nloc & 7);
                    Sout[m2 * 192 + col] = (_Float16)(acc[i][j][r] + bv);
                }
            }
        }
    }
    __syncthreads();

    // ---- epilogue stage 2: coalesced f16x8 stores for q/k chunks
    {
        const int rowt = tid >> 3, cd = tid & 7;
#pragma unroll
        for (int c = 0; c < 3; ++c) {
            const int n64 = n0 + c * 64;
            const int tq = n64 >> 10;
            if (tq == 2) continue;
            const int h = (n64 >> 6) & 15;
#pragma unroll
            for (int pp = 0; pp < 4; ++pp) {
                const int mloc = pp * 64 + rowt;
                const int mb = m0 + mloc;
                const int bb = mb >> 11, sb = mb & 2047;
                f16x8 v = *(const f16x8*)&Sout[mloc * 192 + c * 64
                                               + ((cd ^ (mloc & 7)) << 3)];
                const size_t roff = ((size_t)(bb * 16 + h) * 2048 + sb) * 64;
                if (tq == 1) {
                    const int pos = cd ^ (sb & 7);
                    *(f16x8*)(base + HBUF + roff + pos * 8) = v;
                } else {
                    *(f16x8*)(base + roff + cd * 8) = v;
                }
            }
        }
    }
#undef SA_P
#undef SB_P
}

// ---------------------------------------------------------------------------
// Dense projection GEMM on the qkv template: 128x128 tile, 256 blocks = 1/CU,
// BK=64, 8 waves, XOR-8 pre-swizzled-source staging, 1 vmcnt(0)+barrier/tile.
// ---------------------------------------------------------------------------
__global__ __launch_bounds__(512, 1) void dense_gemm8(
    const _Float16* __restrict__ A, const _Float16* __restrict__ Bt,
    const float* __restrict__ bias, float* __restrict__ C)
{
    __shared__ _Float16 SA[2][8192];    // 128 rows x 64
    __shared__ _Float16 SB[2][8192];
    const int tid = threadIdx.x;
    const int w = tid >> 6, l = tid & 63;
    const int a = l & 15, q4 = l >> 4, a7 = a & 7;
    const int xc = blockIdx.x & 7, loc = blockIdx.x >> 3;
    const int bx = loc >> 2;            // 0..7
    const int by = xc * 4 + (loc & 3);  // 0..31
    const int m0 = by * 128, n0 = bx * 128;
    const int wm = (w >> 2) * 64, wn = (w & 3) * 32;

    const int csw = (((tid & 7) ^ ((tid >> 3) & 7)) << 3);
    const _Float16* gA0 = A  + (size_t)(m0 + (tid >> 3)) * 1024 + csw;
    const _Float16* gB0 = Bt + (size_t)(n0 + (tid >> 3)) * 1024 + csw;

    auto stage = [&](int kt, int sl) {
        const size_t ko = (size_t)kt * 64;
        GLDS16(gA0 + ko,                     &SA[sl][0] + tid * 8);
        GLDS16(gA0 + (size_t)64 * 1024 + ko, &SA[sl][0] + 4096 + tid * 8);
        GLDS16(gB0 + ko,                     &SB[sl][0] + tid * 8);
        GLDS16(gB0 + (size_t)64 * 1024 + ko, &SB[sl][0] + 4096 + tid * 8);
    };

    stage(0, 0); stage(1, 1);
    asm volatile("s_waitcnt vmcnt(4)" ::: "memory");
    __builtin_amdgcn_sched_barrier(0);
    __builtin_amdgcn_s_barrier();
    __builtin_amdgcn_sched_barrier(0);

    f32x4 acc[4][2];
#pragma unroll
    for (int i = 0; i < 4; ++i)
#pragma unroll
        for (int j = 0; j < 2; ++j) acc[i][j] = (f32x4){0.f, 0.f, 0.f, 0.f};

#define FRG(SP, row_, ks_) \
    (*(const f16x8*)&(SP)[(row_) * 64 + ((((ks_) * 4 + q4) ^ a7) << 3)])

    for (int t = 0; t < 16; ++t) {
        const int sl = t & 1, nsl = sl ^ 1;
        const _Float16* sA = &SA[sl][0];
        const _Float16* sB = &SB[sl][0];

        if (t >= 1 && t <= 14) stage(t + 1, nsl);

        f16x8 af[4][2], bfr[2][2];
#pragma unroll
        for (int j = 0; j < 2; ++j) {
            bfr[j][0] = FRG(sB, wn + j * 16 + a, 0);
            bfr[j][1] = FRG(sB, wn + j * 16 + a, 1);
        }
#pragma unroll
        for (int i = 0; i < 4; ++i) {
            af[i][0] = FRG(sA, wm + i * 16 + a, 0);
            af[i][1] = FRG(sA, wm + i * 16 + a, 1);
        }
        __builtin_amdgcn_s_setprio(1);
#pragma unroll
        for (int i = 0; i < 4; ++i)
#pragma unroll
            for (int j = 0; j < 2; ++j) {
                acc[i][j] = MFMA16(af[i][0], bfr[j][0], acc[i][j]);
                acc[i][j] = MFMA16(af[i][1], bfr[j][1], acc[i][j]);
            }
        __builtin_amdgcn_s_setprio(0);

        if (t < 15) {
            asm volatile("s_waitcnt vmcnt(0)" ::: "memory");
            __builtin_amdgcn_sched_barrier(0);
            __builtin_amdgcn_s_barrier();
            __builtin_amdgcn_sched_barrier(0);
        }
    }
#undef FRG

#pragma unroll
    for (int j = 0; j < 2; ++j) {
        const int n = n0 + wn + 16 * j + a;
        const float bv = bias[n];
#pragma unroll
        for (int i = 0; i < 4; ++i)
#pragma unroll
            for (int r = 0; r < 4; ++r) {
                const int m = m0 + wm + 16 * i + q4 * 4 + r;
                C[(size_t)m * 1024 + n] = acc[i][j][r] + bv;
            }
    }
}

// ---------------------------------------------------------------------------
// Paired-tile flash attention (r6 structure + V-fragment hoist, r9-verified).
// ctx store PLAIN (dense GEMM swizzles via staging addresses).
// ---------------------------------------------------------------------------
__global__ __launch_bounds__(256, 2) void attn_mfma(
    const _Float16* __restrict__ qb, const _Float16* __restrict__ kb,
    const _Float16* __restrict__ vtb, _Float16* __restrict__ ctx)
{
    __shared__ _Float16 Ks[2][64 * 64];
    __shared__ _Float16 VT[2][64 * 64];
    __shared__ _Float16 Ps[4][16 * 64];

    const int bid = blockIdx.x;
    const int jj = bid >> 3;
    const int bhIdx = (bid & 7) * 4 + (jj >> 4);   // 0..31
    const int p = jj & 15;
    const int b = bhIdx >> 4, h = bhIdx & 15;
    const int tid = threadIdx.x;
    const int w = tid >> 6, l = tid & 63;
    const int a = l & 15, q4 = l >> 4, a7 = a & 7;
    const size_t bh  = ((size_t)b * NHEAD + h) * SEQ;
    const size_t bhd = ((size_t)b * NHEAD + h) * 64;

    const int qHi = (31 - p) * 64 + w * 16;
    const int qLo = p * 64 + w * 16;
    const int ntiles = 32 - p;

    f16x8 qfh[2], qfl[2];
    {
        const _Float16* qp = qb + (bh + qHi + a) * 64;
        qfh[0] = *(const f16x8*)(qp + q4 * 8);
        qfh[1] = *(const f16x8*)(qp + 32 + q4 * 8);
        const _Float16* ql = qb + (bh + qLo + a) * 64;
        qfl[0] = *(const f16x8*)(ql + q4 * 8);
        qfl[1] = *(const f16x8*)(ql + 32 + q4 * 8);
    }

    f32x4 Oh[4], Ol[4];
#pragma unroll
    for (int c = 0; c < 4; ++c) {
        Oh[c] = (f32x4){0.f, 0.f, 0.f, 0.f};
        Ol[c] = (f32x4){0.f, 0.f, 0.f, 0.f};
    }
    float lh = 0.f, ll = 0.f;

    const _Float16* kg = kb + (bh + w * 16) * 64 + l * 8;
    const int vrow = w * 16 + (l >> 3);
    const _Float16* vg = vtb + (bhd + vrow) * 2048 + (l & 7) * 8;
    _Float16* pbuf = &Ps[w][0];
    const int p0 = (q4 ^ a7) << 3;

    auto stage = [&](int t, int buf) {
        _Float16* ksl = &Ks[buf][0] + w * 1024 + l * 8;
        const _Float16* kt = kg + (size_t)t * 4096;
        GLDS16(kt,       ksl);
        GLDS16(kt + 512, ksl + 512);
        _Float16* vtl = &VT[buf][0] + vrow * 64 + (l & 7) * 8;
        GLDS16(vg + t * 64,            vtl);
        GLDS16(vg + t * 64 + 8 * 2048, vtl + 512);
    };

    stage(0, 0);

    for (int t = 0; t < ntiles; ++t) {
        __syncthreads();                 // tile t landed; prev-iter LDS reads drained
        if (t + 1 < ntiles) stage(t + 1, (t + 1) & 1);

        const _Float16* ksb  = &Ks[t & 1][0];
        const _Float16* vbuf = &VT[t & 1][0];
        const int kt0 = t * 64;
        const bool doLo = (t <= p);

        // ---- V fragments hoisted: one LDS read set per tile, shared hi/lo
        f16x8 vf[4][2];
#pragma unroll
        for (int c = 0; c < 4; ++c) {
            vf[c][0] = *(const f16x8*)&vbuf[(c * 16 + a) * 64 + p0];
            vf[c][1] = *(const f16x8*)&vbuf[(c * 16 + a) * 64 + (p0 ^ 32)];
        }

        f32x4 sh[4], sl[4];
        __builtin_amdgcn_s_setprio(1);
#pragma unroll
        for (int n0 = 0; n0 < 4; ++n0) {
            f16x8 kf0 = *(const f16x8*)&ksb[(n0 * 16 + a) * 64 + p0];
            f16x8 kf1 = *(const f16x8*)&ksb[(n0 * 16 + a) * 64 + (p0 ^ 32)];
            f32x4 c = (f32x4){0.f, 0.f, 0.f, 0.f};
            c = MFMA16(kf0, qfh[0], c);
            c = MFMA16(kf1, qfh[1], c);
            sh[n0] = c;
            if (doLo) {
                f32x4 d = (f32x4){0.f, 0.f, 0.f, 0.f};
                d = MFMA16(kf0, qfl[0], d);
                d = MFMA16(kf1, qfl[1], d);
                sl[n0] = d;
            }
        }
        __builtin_amdgcn_s_setprio(0);

        auto half_step = [&](f32x4 st[4], float& lrun, f32x4* O,
                             const bool maskT, const int qbase) {
            if (maskT) {
#pragma unroll
                for (int n0 = 0; n0 < 4; ++n0)
#pragma unroll
                    for (int r = 0; r < 4; ++r) {
                        const int kgl = kt0 + n0 * 16 + q4 * 4 + r;
                        st[n0][r] = (kgl > qbase + a) ? MASKV
                                                      : fmaf(st[n0][r], SCALE2, BIAS2);
                    }
            } else {
#pragma unroll
                for (int n0 = 0; n0 < 4; ++n0)
#pragma unroll
                    for (int r = 0; r < 4; ++r)
                        st[n0][r] = fmaf(st[n0][r], SCALE2, BIAS2);
            }
            float ls = 0.f;
#pragma unroll
            for (int n0 = 0; n0 < 4; ++n0)
#pragma unroll
                for (int r = 0; r < 4; ++r) {
                    const float pe = EXP2F(st[n0][r]);
                    st[n0][r] = pe;
                    ls += pe;
                }
            lrun += ls;
            // P write: keys 16n0+4q4..+3 consecutive -> one b64 per n0
#pragma unroll
            for (int n0 = 0; n0 < 4; ++n0) {
                f16x4 pk;
#pragma unroll
                for (int r = 0; r < 4; ++r) pk[r] = (_Float16)st[n0][r];
                const int pos = (2 * n0 + (q4 >> 1)) ^ a7;
                *(f16x4*)&pbuf[a * 64 + pos * 8 + ((q4 & 1) << 2)] = pk;
            }
            f16x8 pf0 = *(const f16x8*)&pbuf[a * 64 + p0];
            f16x8 pf1 = *(const f16x8*)&pbuf[a * 64 + (p0 ^ 32)];
            __builtin_amdgcn_s_setprio(1);
#pragma unroll
            for (int c = 0; c < 4; ++c) {
                O[c] = MFMA16(vf[c][0], pf0, O[c]);
                O[c] = MFMA16(vf[c][1], pf1, O[c]);
            }
            __builtin_amdgcn_s_setprio(0);
        };

        half_step(sh, lh, Oh, t == 31 - p, qHi);
        if (doLo) half_step(sl, ll, Ol, t == p, qLo);
    }

    // ---- epilogue: reduce l, normalize, store ctx fp16 PLAIN [b*S+q][h*64+d]
    auto finish = [&](float lrun, const f32x4* O, const int qbase) {
        float lt = lrun;
        lt += __shfl_xor(lt, 16);
        lt += __shfl_xor(lt, 32);
        const float inv = 1.0f / lt;
        const size_t row = (size_t)b * SEQ + qbase + a;
#pragma unroll
        for (int c = 0; c < 4; ++c) {
            const int kcol = h * 64 + c * 16 + q4 * 4;
            f16x4 ov;
#pragma unroll
            for (int r = 0; r < 4; ++r) ov[r] = (_Float16)(O[c][r] * inv);
            *(f16x4*)(ctx + row * HID + kcol) = ov;
        }
    };
    finish(lh, Oh, qHi);
    finish(ll, Ol, qLo);
}

// ---------------------------------------------------------------------------
// WS: [A_h][WqkvT][WdT][q|k(sw)|v(unused)|vT(sw)][ctx]  (all fp16)
// ---------------------------------------------------------------------------
extern "C" void kernel_launch(void* const* d_in, const int* in_sizes, int n_in,
                              void* d_out, int out_size, void* d_ws, size_t ws_size,
                              hipStream_t stream) {
    const float* hs   = (const float*)d_in[0];
    const float* Wqkv = (const float*)d_in[2];
    const float* bqkv = (const float*)d_in[3];
    const float* Wd   = (const float*)d_in[4];
    const float* bd   = (const float*)d_in[5];

    _Float16* A_h   = (_Float16*)d_ws;
    _Float16* WqkvT = A_h + (size_t)MTOT * HID;
    _Float16* WdT   = WqkvT + (size_t)QKVN * HID;
    _Float16* qbuf  = WdT + (size_t)HID * HID;            // q | k(sw) | (v) | vT(sw)
    _Float16* ctxb  = qbuf + 4 * HBUF;

    prep_kernel<<<6144, 256, 0, stream>>>(hs, Wqkv, Wd, A_h, WqkvT, WdT);

    qkv_gemm8<<<256, 512, 0, stream>>>(A_h, WqkvT, bqkv, qbuf);

    attn_mfma<<<512, 256, 0, stream>>>(
        qbuf, qbuf + HBUF, qbuf + 3 * HBUF, ctxb);

    dense_gemm8<<<256, 512, 0, stream>>>(ctxb, WdT, bd, (float*)d_out);
}

// Round 12
// 177.377 us; speedup vs baseline: 1.4705x; 1.0028x over previous
//
#include <hip/hip_runtime.h>
#include <math.h>

#define BATCH 2
#define SEQ   2048
#define HID   1024
#define NHEAD 16
#define HDIM  64
#define MTOT  (BATCH * SEQ)   // 4096
#define QKVN  (3 * HID)       // 3072
#define HBUF  ((size_t)BATCH * NHEAD * SEQ * HDIM)   // elems per q/k/v/vT buf

typedef _Float16 f16x8 __attribute__((ext_vector_type(8)));
typedef _Float16 f16x4 __attribute__((ext_vector_type(4)));
typedef float    f32x4 __attribute__((ext_vector_type(4)));

#define MFMA16(a, b, c) __builtin_amdgcn_mfma_f32_16x16x32_f16((a), (b), (c), 0, 0, 0)

#define GLDS16(gp, lp) __builtin_amdgcn_global_load_lds( \
    (const __attribute__((address_space(1))) void*)(gp), \
    (__attribute__((address_space(3))) void*)(lp), 16, 0, 0)

#if __has_builtin(__builtin_amdgcn_exp2f)
#define EXP2F(x) __builtin_amdgcn_exp2f(x)
#else
#define EXP2F(x) exp2f(x)
#endif

#define SCALE2 0.18033688011f     // 0.125 * log2(e)
#define MASKV  -14426.950408f     // -10000 * log2(e)  -> exp2 == 0 exactly
#define BIAS2  -4.0f              // headroom shift; cancels in normalization

// ---------------------------------------------------------------------------
// Fused prep:
//   blocks [0,2048):    hs fp32 -> fp16 PLAIN row-major [m][1024] (float4 x2)
//   blocks [2048,6144): Wqkv / Wd fp32 [K][N] -> fp16 PLAIN [N][K]
// ---------------------------------------------------------------------------
__global__ __launch_bounds__(256) void prep_kernel(
    const float* __restrict__ hs, const float* __restrict__ Wqkv,
    const float* __restrict__ Wd, _Float16* __restrict__ A_h,
    _Float16* __restrict__ outQ, _Float16* __restrict__ outD)
{
    __shared__ _Float16 T[32][36];
    const int gid = blockIdx.x;
    const int tid = threadIdx.x;
    if (gid < 2048) {
        const int ci = gid * 256 + tid;
        const int m = ci >> 7, cc = ci & 127;
        const float* src = hs + (size_t)m * 1024 + cc * 8;
        const float4 v0 = *(const float4*)(src);
        const float4 v1 = *(const float4*)(src + 4);
        f16x8 o;
        o[0] = (_Float16)v0.x; o[1] = (_Float16)v0.y;
        o[2] = (_Float16)v0.z; o[3] = (_Float16)v0.w;
        o[4] = (_Float16)v1.x; o[5] = (_Float16)v1.y;
        o[6] = (_Float16)v1.z; o[7] = (_Float16)v1.w;
        *(f16x8*)(A_h + (size_t)m * 1024 + cc * 8) = o;
        return;
    }
    const int tb = gid - 2048;
    const int bx = tb & 127, k0 = (tb >> 7) * 32;
    const float* in;
    _Float16* out;
    int N, n0;
    if (bx < 96) { in = Wqkv; out = outQ; N = QKVN; n0 = bx * 32; }
    else         { in = Wd;   out = outD; N = HID;  n0 = (bx - 96) * 32; }
    {
        const int r = tid >> 3, c4 = (tid & 7) * 4;
        float4 v = *(const float4*)(in + (size_t)(k0 + r) * N + n0 + c4);
        T[r][c4 + 0] = (_Float16)v.x;
        T[r][c4 + 1] = (_Float16)v.y;
        T[r][c4 + 2] = (_Float16)v.z;
        T[r][c4 + 3] = (_Float16)v.w;
    }
    __syncthreads();
    {
        const int nn = tid >> 3, k4 = (tid & 7) * 4;
        const int n = n0 + nn;
        f16x4 o;
        o[0] = T[k4 + 0][nn]; o[1] = T[k4 + 1][nn];
        o[2] = T[k4 + 2][nn]; o[3] = T[k4 + 3][nn];
        *(f16x4*)(out + (size_t)n * 1024 + k0 + k4) = o;   // plain [N][K]
    }
}

// ---------------------------------------------------------------------------
// QKV GEMM, 256x192 tile, grid 16x16 = 256 blocks = 1/CU. (r11-verified:
// LDS epilogue transpose -> coalesced f16x8 q/k stores)
// ---------------------------------------------------------------------------
__global__ __launch_bounds__(512, 1) void qkv_gemm8(
    const _Float16* __restrict__ A, const _Float16* __restrict__ Bt,
    const float* __restrict__ bias, _Float16* __restrict__ base)
{
    __shared__ _Float16 SMEM[57344];   // 112 KB: A0|A1|B0|B1, reused as Sout
#define SA_P(sl) (SMEM + (sl) * 16384)
#define SB_P(sl) (SMEM + 32768 + (sl) * 12288)

    const int tid = threadIdx.x;
    const int w = tid >> 6, l = tid & 63;
    const int a = l & 15, q4 = l >> 4, a7 = a & 7;
    const int xc = blockIdx.x & 7, loc = blockIdx.x >> 3;
    const int bx = (xc & 3) * 4 + (loc & 3);
    const int by = (xc >> 2) * 8 + (loc >> 2);
    const int m0 = by * 256, n0 = bx * 192;
    const int wm = (w >> 2) * 128, wn = (w & 3) * 48;

    const int csw = (((tid & 7) ^ ((tid >> 3) & 7)) << 3);
    const _Float16* gA0 = A  + (size_t)(m0 + (tid >> 3)) * 1024 + csw;
    const _Float16* gB0 = Bt + (size_t)(n0 + (tid >> 3)) * 1024 + csw;

    auto stage = [&](int kt, int sl) {
        const size_t ko = (size_t)kt * 64;
#pragma unroll
        for (int u = 0; u < 4; ++u)
            GLDS16(gA0 + (size_t)(u * 64) * 1024 + ko, SA_P(sl) + u * 4096 + tid * 8);
#pragma unroll
        for (int u = 0; u < 3; ++u)
            GLDS16(gB0 + (size_t)(u * 64) * 1024 + ko, SB_P(sl) + u * 4096 + tid * 8);
    };

    stage(0, 0); stage(1, 1);
    asm volatile("s_waitcnt vmcnt(7)" ::: "memory");
    __builtin_amdgcn_sched_barrier(0);
    __builtin_amdgcn_s_barrier();
    __builtin_amdgcn_sched_barrier(0);

    f32x4 acc[8][3];
#pragma unroll
    for (int i = 0; i < 8; ++i)
#pragma unroll
        for (int j = 0; j < 3; ++j) acc[i][j] = (f32x4){0.f, 0.f, 0.f, 0.f};

#define FRG(SP, row_, ks_) \
    (*(const f16x8*)&(SP)[(row_) * 64 + ((((ks_) * 4 + q4) ^ a7) << 3)])

    f16x8 aL[4][2], aH[4][2], bf[3][2];
    {
#pragma unroll
        for (int i = 0; i < 4; ++i) {
            aL[i][0] = FRG(SA_P(0), wm + i * 16 + a, 0);
            aL[i][1] = FRG(SA_P(0), wm + i * 16 + a, 1);
        }
#pragma unroll
        for (int j = 0; j < 2; ++j) {
            bf[j][0] = FRG(SB_P(0), wn + j * 16 + a, 0);
            bf[j][1] = FRG(SB_P(0), wn + j * 16 + a, 1);
        }
    }

    for (int t = 0; t < 16; ++t) {
        const int sl = t & 1, nsl = sl ^ 1;
        const _Float16* sA = SA_P(sl);
        const _Float16* sB = SB_P(sl);

        if (t >= 1 && t <= 14) stage(t + 1, nsl);

        __builtin_amdgcn_s_setprio(1);
#pragma unroll
        for (int i = 0; i < 4; ++i)
#pragma unroll
            for (int j = 0; j < 2; ++j) {
                acc[i][j] = MFMA16(aL[i][0], bf[j][0], acc[i][j]);
                acc[i][j] = MFMA16(aL[i][1], bf[j][1], acc[i][j]);
            }
        __builtin_amdgcn_s_setprio(0);

        bf[2][0] = FRG(sB, wn + 32 + a, 0);
        bf[2][1] = FRG(sB, wn + 32 + a, 1);
        __builtin_amdgcn_s_setprio(1);
#pragma unroll
        for (int i = 0; i < 4; ++i) {
            acc[i][2] = MFMA16(aL[i][0], bf[2][0], acc[i][2]);
            acc[i][2] = MFMA16(aL[i][1], bf[2][1], acc[i][2]);
        }
        __builtin_amdgcn_s_setprio(0);

#pragma unroll
        for (int i = 0; i < 4; ++i) {
            aH[i][0] = FRG(sA, wm + 64 + i * 16 + a, 0);
            aH[i][1] = FRG(sA, wm + 64 + i * 16 + a, 1);
        }
        __builtin_amdgcn_s_setprio(1);
#pragma unroll
        for (int i = 0; i < 4; ++i)
#pragma unroll
            for (int j = 0; j < 3; ++j) {
                acc[i + 4][j] = MFMA16(aH[i][0], bf[j][0], acc[i + 4][j]);
                acc[i + 4][j] = MFMA16(aH[i][1], bf[j][1], acc[i + 4][j]);
            }
        __builtin_amdgcn_s_setprio(0);

        if (t < 15) {
            asm volatile("s_waitcnt vmcnt(0)" ::: "memory");
            __builtin_amdgcn_sched_barrier(0);
            __builtin_amdgcn_s_barrier();
            __builtin_amdgcn_sched_barrier(0);
            const _Float16* nA = SA_P(nsl);
            const _Float16* nB = SB_P(nsl);
#pragma unroll
            for (int i = 0; i < 4; ++i) {
                aL[i][0] = FRG(nA, wm + i * 16 + a, 0);
                aL[i][1] = FRG(nA, wm + i * 16 + a, 1);
            }
#pragma unroll
            for (int j = 0; j < 2; ++j) {
                bf[j][0] = FRG(nB, wn + j * 16 + a, 0);
                bf[j][1] = FRG(nB, wn + j * 16 + a, 1);
            }
        }
    }
#undef FRG

    // ---- epilogue stage 1: acc -> Sout (q/k) with chunk-XOR swizzle;
    //      vT chunk keeps the direct f16x4 scatter.
    __syncthreads();                     // all frag reads done; SMEM reusable
    _Float16* const Sout = SMEM;         // [256][192], col chunk ^= row&7
#pragma unroll
    for (int j = 0; j < 3; ++j) {
        const int n = n0 + wn + 16 * j + a;
        const float bv = bias[n];
        const int tq = n >> 10, h = (n >> 6) & 15, d = n & 63;
        const int nloc = wn + 16 * j + a;
#pragma unroll
        for (int i = 0; i < 8; ++i) {
            const int mloc = wm + 16 * i + q4 * 4;
            if (tq == 2) {
                const int mb = m0 + mloc;
                const int bb = mb >> 11, sb = mb & 2047;
                f16x4 ov;
#pragma unroll
                for (int r = 0; r < 4; ++r) ov[r] = (_Float16)(acc[i][j][r] + bv);
                const size_t off =
                    ((size_t)((bb * 16 + h) * 64 + d)) * 2048
                    + (sb & ~63)
                    + ((((sb >> 3) & 7) ^ (d & 7)) << 3) + (sb & 7);
                *(f16x4*)(base + 3 * HBUF + off) = ov;
            } else {
#pragma unroll
                for (int r = 0; r < 4; ++r) {
                    const int m2 = mloc + r;
                    const int col = (nloc & 0xC0)
                                  + (((((nloc >> 3) & 7)) ^ (m2 & 7)) << 3)
                                  + (nloc & 7);
                    Sout[m2 * 192 + col] = (_Float16)(acc[i][j][r] + bv);
                }
            }
        }
    }
    __syncthreads();

    // ---- epilogue stage 2: coalesced f16x8 stores for q/k chunks
    {
        const int rowt = tid >> 3, cd = tid & 7;
#pragma unroll
        for (int c = 0; c < 3; ++c) {
            const int n64 = n0 + c * 64;
            const int tq = n64 >> 10;
            if (tq == 2) continue;
            const int h = (n64 >> 6) & 15;
#pragma unroll
            for (int pp = 0; pp < 4; ++pp) {
                const int mloc = pp * 64 + rowt;
                const int mb = m0 + mloc;
                const int bb = mb >> 11, sb = mb & 2047;
                f16x8 v = *(const f16x8*)&Sout[mloc * 192 + c * 64
                                               + ((cd ^ (mloc & 7)) << 3)];
                const size_t roff = ((size_t)(bb * 16 + h) * 2048 + sb) * 64;
                if (tq == 1) {
                    const int pos = cd ^ (sb & 7);
                    *(f16x8*)(base + HBUF + roff + pos * 8) = v;
                } else {
                    *(f16x8*)(base + roff + cd * 8) = v;
                }
            }
        }
    }
#undef SA_P
#undef SB_P
}

// ---------------------------------------------------------------------------
// Dense projection GEMM on the qkv template: 128x128 tile, 256 blocks = 1/CU,
// BK=64, 8 waves, XOR-8 pre-swizzled-source staging, 1 vmcnt(0)+barrier/tile.
// ---------------------------------------------------------------------------
__global__ __launch_bounds__(512, 1) void dense_gemm8(
    const _Float16* __restrict__ A, const _Float16* __restrict__ Bt,
    const float* __restrict__ bias, float* __restrict__ C)
{
    __shared__ _Float16 SA[2][8192];    // 128 rows x 64
    __shared__ _Float16 SB[2][8192];
    const int tid = threadIdx.x;
    const int w = tid >> 6, l = tid & 63;
    const int a = l & 15, q4 = l >> 4, a7 = a & 7;
    const int xc = blockIdx.x & 7, loc = blockIdx.x >> 3;
    const int bx = loc >> 2;            // 0..7
    const int by = xc * 4 + (loc & 3);  // 0..31
    const int m0 = by * 128, n0 = bx * 128;
    const int wm = (w >> 2) * 64, wn = (w & 3) * 32;

    const int csw = (((tid & 7) ^ ((tid >> 3) & 7)) << 3);
    const _Float16* gA0 = A  + (size_t)(m0 + (tid >> 3)) * 1024 + csw;
    const _Float16* gB0 = Bt + (size_t)(n0 + (tid >> 3)) * 1024 + csw;

    auto stage = [&](int kt, int sl) {
        const size_t ko = (size_t)kt * 64;
        GLDS16(gA0 + ko,                     &SA[sl][0] + tid * 8);
        GLDS16(gA0 + (size_t)64 * 1024 + ko, &SA[sl][0] + 4096 + tid * 8);
        GLDS16(gB0 + ko,                     &SB[sl][0] + tid * 8);
        GLDS16(gB0 + (size_t)64 * 1024 + ko, &SB[sl][0] + 4096 + tid * 8);
    };

    stage(0, 0); stage(1, 1);
    asm volatile("s_waitcnt vmcnt(4)" ::: "memory");
    __builtin_amdgcn_sched_barrier(0);
    __builtin_amdgcn_s_barrier();
    __builtin_amdgcn_sched_barrier(0);

    f32x4 acc[4][2];
#pragma unroll
    for (int i = 0; i < 4; ++i)
#pragma unroll
        for (int j = 0; j < 2; ++j) acc[i][j] = (f32x4){0.f, 0.f, 0.f, 0.f};

#define FRG(SP, row_, ks_) \
    (*(const f16x8*)&(SP)[(row_) * 64 + ((((ks_) * 4 + q4) ^ a7) << 3)])

    for (int t = 0; t < 16; ++t) {
        const int sl = t & 1, nsl = sl ^ 1;
        const _Float16* sA = &SA[sl][0];
        const _Float16* sB = &SB[sl][0];

        if (t >= 1 && t <= 14) stage(t + 1, nsl);

        f16x8 af[4][2], bfr[2][2];
#pragma unroll
        for (int j = 0; j < 2; ++j) {
            bfr[j][0] = FRG(sB, wn + j * 16 + a, 0);
            bfr[j][1] = FRG(sB, wn + j * 16 + a, 1);
        }
#pragma unroll
        for (int i = 0; i < 4; ++i) {
            af[i][0] = FRG(sA, wm + i * 16 + a, 0);
            af[i][1] = FRG(sA, wm + i * 16 + a, 1);
        }
        __builtin_amdgcn_s_setprio(1);
#pragma unroll
        for (int i = 0; i < 4; ++i)
#pragma unroll
            for (int j = 0; j < 2; ++j) {
                acc[i][j] = MFMA16(af[i][0], bfr[j][0], acc[i][j]);
                acc[i][j] = MFMA16(af[i][1], bfr[j][1], acc[i][j]);
            }
        __builtin_amdgcn_s_setprio(0);

        if (t < 15) {
            asm volatile("s_waitcnt vmcnt(0)" ::: "memory");
            __builtin_amdgcn_sched_barrier(0);
            __builtin_amdgcn_s_barrier();
            __builtin_amdgcn_sched_barrier(0);
        }
    }
#undef FRG

#pragma unroll
    for (int j = 0; j < 2; ++j) {
        const int n = n0 + wn + 16 * j + a;
        const float bv = bias[n];
#pragma unroll
        for (int i = 0; i < 4; ++i)
#pragma unroll
            for (int r = 0; r < 4; ++r) {
                const int m = m0 + wm + 16 * i + q4 * 4 + r;
                C[(size_t)m * 1024 + n] = acc[i][j][r] + bv;
            }
    }
}

// ---------------------------------------------------------------------------
// Paired-tile flash attention — 2-tiles-per-barrier variant.
// 4-slot K/V ring (72 KB LDS, still 2 blocks/CU). Per iteration:
// {__syncthreads; stage t+2,t+3; process t; process t+1} -> barrier count
// 33 -> 17; staged loads are ~2 compute-tiles old at their drain (vs 1);
// tile t+1's LDS frag reads overlap tile t's softmax/PV with no barrier
// between. Slot safety: slot (t+2)&3 was last read at iter t-2, two
// full-drain barriers ago. Layouts/masking/epilogue identical to r11.
// ---------------------------------------------------------------------------
__global__ __launch_bounds__(256, 2) void attn_mfma(
    const _Float16* __restrict__ qb, const _Float16* __restrict__ kb,
    const _Float16* __restrict__ vtb, _Float16* __restrict__ ctx)
{
    __shared__ _Float16 Ks[4][64 * 64];
    __shared__ _Float16 VT[4][64 * 64];
    __shared__ _Float16 Ps[4][16 * 64];

    const int bid = blockIdx.x;
    const int jj = bid >> 3;
    const int bhIdx = (bid & 7) * 4 + (jj >> 4);   // 0..31
    const int p = jj & 15;
    const int b = bhIdx >> 4, h = bhIdx & 15;
    const int tid = threadIdx.x;
    const int w = tid >> 6, l = tid & 63;
    const int a = l & 15, q4 = l >> 4, a7 = a & 7;
    const size_t bh  = ((size_t)b * NHEAD + h) * SEQ;
    const size_t bhd = ((size_t)b * NHEAD + h) * 64;

    const int qHi = (31 - p) * 64 + w * 16;
    const int qLo = p * 64 + w * 16;
    const int ntiles = 32 - p;

    f16x8 qfh[2], qfl[2];
    {
        const _Float16* qp = qb + (bh + qHi + a) * 64;
        qfh[0] = *(const f16x8*)(qp + q4 * 8);
        qfh[1] = *(const f16x8*)(qp + 32 + q4 * 8);
        const _Float16* ql = qb + (bh + qLo + a) * 64;
        qfl[0] = *(const f16x8*)(ql + q4 * 8);
        qfl[1] = *(const f16x8*)(ql + 32 + q4 * 8);
    }

    f32x4 Oh[4], Ol[4];
#pragma unroll
    for (int c = 0; c < 4; ++c) {
        Oh[c] = (f32x4){0.f, 0.f, 0.f, 0.f};
        Ol[c] = (f32x4){0.f, 0.f, 0.f, 0.f};
    }
    float lh = 0.f, ll = 0.f;

    const _Float16* kg = kb + (bh + w * 16) * 64 + l * 8;
    const int vrow = w * 16 + (l >> 3);
    const _Float16* vg = vtb + (bhd + vrow) * 2048 + (l & 7) * 8;
    _Float16* pbuf = &Ps[w][0];
    const int p0 = (q4 ^ a7) << 3;

    auto stage = [&](int t) {
        const int buf = t & 3;
        _Float16* ksl = &Ks[buf][0] + w * 1024 + l * 8;
        const _Float16* kt = kg + (size_t)t * 4096;
        GLDS16(kt,       ksl);
        GLDS16(kt + 512, ksl + 512);
        _Float16* vtl = &VT[buf][0] + vrow * 64 + (l & 7) * 8;
        GLDS16(vg + t * 64,            vtl);
        GLDS16(vg + t * 64 + 8 * 2048, vtl + 512);
    };

    auto half_step = [&](f32x4 st[4], float& lrun, f32x4* O, const f16x8 vf[4][2],
                         const int kt0, const bool maskT, const int qbase) {
        if (maskT) {
#pragma unroll
            for (int n0 = 0; n0 < 4; ++n0)
#pragma unroll
                for (int r = 0; r < 4; ++r) {
                    const int kgl = kt0 + n0 * 16 + q4 * 4 + r;
                    st[n0][r] = (kgl > qbase + a) ? MASKV
                                                  : fmaf(st[n0][r], SCALE2, BIAS2);
                }
        } else {
#pragma unroll
            for (int n0 = 0; n0 < 4; ++n0)
#pragma unroll
                for (int r = 0; r < 4; ++r)
                    st[n0][r] = fmaf(st[n0][r], SCALE2, BIAS2);
        }
        float ls = 0.f;
#pragma unroll
        for (int n0 = 0; n0 < 4; ++n0)
#pragma unroll
            for (int r = 0; r < 4; ++r) {
                const float pe = EXP2F(st[n0][r]);
                st[n0][r] = pe;
                ls += pe;
            }
        lrun += ls;
        // P write: keys 16n0+4q4..+3 consecutive -> one b64 per n0
#pragma unroll
        for (int n0 = 0; n0 < 4; ++n0) {
            f16x4 pk;
#pragma unroll
            for (int r = 0; r < 4; ++r) pk[r] = (_Float16)st[n0][r];
            const int pos = (2 * n0 + (q4 >> 1)) ^ a7;
            *(f16x4*)&pbuf[a * 64 + pos * 8 + ((q4 & 1) << 2)] = pk;
        }
        f16x8 pf0 = *(const f16x8*)&pbuf[a * 64 + p0];
        f16x8 pf1 = *(const f16x8*)&pbuf[a * 64 + (p0 ^ 32)];
        __builtin_amdgcn_s_setprio(1);
#pragma unroll
        for (int c = 0; c < 4; ++c) {
            O[c] = MFMA16(vf[c][0], pf0, O[c]);
            O[c] = MFMA16(vf[c][1], pf1, O[c]);
        }
        __builtin_amdgcn_s_setprio(0);
    };

    auto process = [&](int t) {
        const int buf = t & 3;
        const _Float16* ksb  = &Ks[buf][0];
        const _Float16* vbuf = &VT[buf][0];
        const int kt0 = t * 64;
        const bool doLo = (t <= p);

        // V fragments: one LDS read set per tile, shared hi/lo
        f16x8 vf[4][2];
#pragma unroll
        for (int c = 0; c < 4; ++c) {
            vf[c][0] = *(const f16x8*)&vbuf[(c * 16 + a) * 64 + p0];
            vf[c][1] = *(const f16x8*)&vbuf[(c * 16 + a) * 64 + (p0 ^ 32)];
        }

        f32x4 sh[4], sl[4];
        __builtin_amdgcn_s_setprio(1);
#pragma unroll
        for (int n0 = 0; n0 < 4; ++n0) {
            f16x8 kf0 = *(const f16x8*)&ksb[(n0 * 16 + a) * 64 + p0];
            f16x8 kf1 = *(const f16x8*)&ksb[(n0 * 16 + a) * 64 + (p0 ^ 32)];
            f32x4 c = (f32x4){0.f, 0.f, 0.f, 0.f};
            c = MFMA16(kf0, qfh[0], c);
            c = MFMA16(kf1, qfh[1], c);
            sh[n0] = c;
            if (doLo) {
                f32x4 d = (f32x4){0.f, 0.f, 0.f, 0.f};
                d = MFMA16(kf0, qfl[0], d);
                d = MFMA16(kf1, qfl[1], d);
                sl[n0] = d;
            }
        }
        __builtin_amdgcn_s_setprio(0);

        half_step(sh, lh, Oh, vf, kt0, t == 31 - p, qHi);
        if (doLo) half_step(sl, ll, Ol, vf, kt0, t == p, qLo);
    };

    stage(0);
    stage(1);

    for (int tt = 0; tt < ntiles; tt += 2) {
        __syncthreads();                 // tiles tt,tt+1 landed; old reads drained
        if (tt + 2 < ntiles) stage(tt + 2);
        if (tt + 3 < ntiles) stage(tt + 3);
        process(tt);
        if (tt + 1 < ntiles) process(tt + 1);
    }

    // ---- epilogue: reduce l, normalize, store ctx fp16 PLAIN [b*S+q][h*64+d]
    auto finish = [&](float lrun, const f32x4* O, const int qbase) {
        float lt = lrun;
        lt += __shfl_xor(lt, 16);
        lt += __shfl_xor(lt, 32);
        const float inv = 1.0f / lt;
        const size_t row = (size_t)b * SEQ + qbase + a;
#pragma unroll
        for (int c = 0; c < 4; ++c) {
            const int kcol = h * 64 + c * 16 + q4 * 4;
            f16x4 ov;
#pragma unroll
            for (int r = 0; r < 4; ++r) ov[r] = (_Float16)(O[c][r] * inv);
            *(f16x4*)(ctx + row * HID + kcol) = ov;
        }
    };
    finish(lh, Oh, qHi);
    finish(ll, Ol, qLo);
}

// ---------------------------------------------------------------------------
// WS: [A_h][WqkvT][WdT][q|k(sw)|v(unused)|vT(sw)][ctx]  (all fp16)
// ---------------------------------------------------------------------------
extern "C" void kernel_launch(void* const* d_in, const int* in_sizes, int n_in,
                              void* d_out, int out_size, void* d_ws, size_t ws_size,
                              hipStream_t stream) {
    const float* hs   = (const float*)d_in[0];
    const float* Wqkv = (const float*)d_in[2];
    const float* bqkv = (const float*)d_in[3];
    const float* Wd   = (const float*)d_in[4];
    const float* bd   = (const float*)d_in[5];

    _Float16* A_h   = (_Float16*)d_ws;
    _Float16* WqkvT = A_h + (size_t)MTOT * HID;
    _Float16* WdT   = WqkvT + (size_t)QKVN * HID;
    _Float16* qbuf  = WdT + (size_t)HID * HID;            // q | k(sw) | (v) | vT(sw)
    _Float16* ctxb  = qbuf + 4 * HBUF;

    prep_kernel<<<6144, 256, 0, stream>>>(hs, Wqkv, Wd, A_h, WqkvT, WdT);

    qkv_gemm8<<<256, 512, 0, stream>>>(A_h, WqkvT, bqkv, qbuf);

    attn_mfma<<<512, 256, 0, stream>>>(
        qbuf, qbuf + HBUF, qbuf + 3 * HBUF, ctxb);

    dense_gemm8<<<256, 512, 0, stream>>>(ctxb, WdT, bd, (float*)d_out);
}